// Round 18
// baseline (163.638 us; speedup 1.0000x reference)
//
#include <hip/hip_runtime.h>
#include <math.h>

#define N_NODES 100000
#define N_EDGES 1600000
#define NROWS 100032
#define NBUK 782          // dst>>7 -> 0..781 (128 nodes per bucket)
#define BCAP 2600         // entries per bucket region (mean 2046)
#define BINCHUNK 4096     // edges per bin block (256 thr x 16)
#define NBINBLK 391
#define NGEMMBLK 1563     // NROWS/64

typedef unsigned short u16;
typedef u16 u16x4 __attribute__((ext_vector_type(4)));
typedef u16 u16x8 __attribute__((ext_vector_type(8)));
typedef short s16x8 __attribute__((ext_vector_type(8)));
typedef float f32x4 __attribute__((ext_vector_type(4)));

__device__ __forceinline__ float bf2f(u16 u) {
    union { unsigned i; float f; } v; v.i = ((unsigned)u) << 16; return v.f;
}
__device__ __forceinline__ u16 f2bf(float f) {
    union { float f; unsigned i; } v; v.f = f;
    return (u16)((v.i + 0x7FFFu + ((v.i >> 16) & 1u)) >> 16);  // RNE
}

// ------------------------- pre: W split + cursor zeroing (one dispatch) -----
__global__ __launch_bounds__(256) void k_pre(const float* __restrict__ W1,
                                             const float* __restrict__ W2,
                                             u16* __restrict__ w1pre,
                                             u16* __restrict__ w2pre,
                                             int* __restrict__ bucketCursor,
                                             int* __restrict__ totalCursor,
                                             float* __restrict__ dinv) {
    const int t = threadIdx.x;
    const int b = blockIdx.x;
    if (b < 16) {
        #pragma unroll
        for (int half = 0; half < 2; ++half) {
            int e = b * 512 + half * 256 + t;   // e = k*64 + c
            int k = e >> 6, c = e & 63;
            float f = W1[e];
            u16 h = f2bf(f);
            u16 l = f2bf(f - bf2f(h));
            int byte = (c * 256 + k * 2) ^ ((c & 7) << 4);
            *(u16*)((char*)w1pre + byte) = h;
            *(u16*)((char*)w1pre + 16384 + byte) = l;
        }
    } else {
        int e = (b - 16) * 256 + t;
        int k = e >> 6, c = e & 63;
        float f = W2[e];
        u16 h = f2bf(f);
        u16 l = f2bf(f - bf2f(h));
        int byte = (c * 128 + k * 2) ^ ((c & 7) << 4);
        *(u16*)((char*)w2pre + byte) = h;
        *(u16*)((char*)w2pre + 8192 + byte) = l;
    }
    if (b == 0) {
        for (int i = t; i < NBUK; i += 256) bucketCursor[i] = 0;
        if (t == 0) { totalCursor[0] = 0; dinv[N_NODES] = 0.f; }
    }
}

// ---------------------------------------------------------------- binning ---
__global__ __launch_bounds__(256) void k_bin(const int* __restrict__ src,
                                             const int* __restrict__ dst,
                                             int* bucketCursor,
                                             unsigned int* __restrict__ bins) {
    __shared__ int lcnt[NBUK];
    __shared__ int lbase[NBUK];
    const int t = threadIdx.x;
    for (int i = t; i < NBUK; i += 256) lcnt[i] = 0;
    __syncthreads();

    const int e0 = blockIdx.x * BINCHUNK + t * 16;
    int4 s4[4], d4[4];
    int bkt[16], rnk[16];
    const bool valid = e0 < N_EDGES;   // N_EDGES % 16 == 0
    if (valid) {
        #pragma unroll
        for (int k = 0; k < 4; ++k) {
            s4[k] = *(const int4*)(src + e0 + 4 * k);
            d4[k] = *(const int4*)(dst + e0 + 4 * k);
        }
        #pragma unroll
        for (int k = 0; k < 4; ++k) {
            int dd[4] = { d4[k].x, d4[k].y, d4[k].z, d4[k].w };
            #pragma unroll
            for (int j = 0; j < 4; ++j) {
                int b = dd[j] >> 7;
                bkt[4 * k + j] = b;
                rnk[4 * k + j] = atomicAdd(&lcnt[b], 1);
            }
        }
    }
    __syncthreads();
    for (int i = t; i < NBUK; i += 256)
        if (lcnt[i] > 0) lbase[i] = atomicAdd(&bucketCursor[i], lcnt[i]);
    __syncthreads();
    if (valid) {
        #pragma unroll
        for (int k = 0; k < 4; ++k) {
            int ss[4] = { s4[k].x, s4[k].y, s4[k].z, s4[k].w };
            int dd[4] = { d4[k].x, d4[k].y, d4[k].z, d4[k].w };
            #pragma unroll
            for (int j = 0; j < 4; ++j) {
                int i = 4 * k + j;
                unsigned w = ((unsigned)(dd[j] & 127) << 17) | (unsigned)ss[j];
                bins[(size_t)bkt[i] * BCAP + lbase[bkt[i]] + rnk[i]] = w;
            }
        }
    }
}

// -------------------------------- quantized-row epilogue helper (device) ----
__device__ __forceinline__ void quant_store_row(float v0, float v1, float v2, float v3,
                                                int row, int l16,
                                                signed char* __restrict__ H8,
                                                float* __restrict__ scale) {
    float m = fmaxf(fmaxf(fabsf(v0), fabsf(v1)), fmaxf(fabsf(v2), fabsf(v3)));
    m = fmaxf(m, __shfl_xor(m, 1));
    m = fmaxf(m, __shfl_xor(m, 2));
    m = fmaxf(m, __shfl_xor(m, 4));
    m = fmaxf(m, __shfl_xor(m, 8));
    float inv = (m > 0.f) ? 127.f / m : 0.f;
    if (l16 == 0) scale[row] = m * (1.f / 127.f);
    size_t base = (size_t)row * 64 + l16;
    H8[base +  0] = (signed char)__float2int_rn(v0 * inv);
    H8[base + 16] = (signed char)__float2int_rn(v1 * inv);
    H8[base + 32] = (signed char)__float2int_rn(v2 * inv);
    H8[base + 48] = (signed char)__float2int_rn(v3 * inv);
}

// ------------------------------------------------------- GEMM1 (MFMA) -------
// hs1 = x @ W1 (UNSCALED; dinv folded into aggregate), int8 rows + scale.
__global__ __launch_bounds__(256) void k_gemm1(const float* __restrict__ X,
                                               const u16* __restrict__ w1pre,
                                               signed char* __restrict__ H8,
                                               float* __restrict__ scale) {
    __shared__ u16 sxh[64 * 128];
    __shared__ u16 sxl[64 * 128];
    __shared__ u16 wth[64 * 128];
    __shared__ u16 wtl[64 * 128];
    const int t = threadIdx.x;
    const int blk = blockIdx.x;

    {
        const float4* Xv = (const float4*)X;
        #pragma unroll
        for (int i = 0; i < 8; ++i) {
            int idx = i * 256 + t;
            int row = idx >> 5;
            int k4  = (idx & 31) << 2;
            int grow = blk * 64 + row;
            float4 v = make_float4(0.f, 0.f, 0.f, 0.f);
            if (grow < N_NODES) v = Xv[(size_t)grow * 32 + (idx & 31)];
            float f[4] = { v.x, v.y, v.z, v.w };
            u16x4 hv, lv;
            #pragma unroll
            for (int j = 0; j < 4; ++j) {
                u16 h = f2bf(f[j]);
                hv[j] = h;
                lv[j] = f2bf(f[j] - bf2f(h));
            }
            int byte = (row * 256 + k4 * 2) ^ ((row & 7) << 4);
            *(u16x4*)((char*)sxh + byte) = hv;
            *(u16x4*)((char*)sxl + byte) = lv;
        }
    }
    {
        const u16x8* G = (const u16x8*)w1pre;
        u16x8* Lh = (u16x8*)wth;
        u16x8* Ll = (u16x8*)wtl;
        #pragma unroll
        for (int i = 0; i < 4; ++i) Lh[i * 256 + t] = G[i * 256 + t];
        #pragma unroll
        for (int i = 0; i < 4; ++i) Ll[i * 256 + t] = G[1024 + i * 256 + t];
    }
    __syncthreads();

    const int lane = t & 63;
    const int w    = t >> 6;
    const int l16  = lane & 15;
    const int kg   = lane >> 4;
    f32x4 acc[4];
    #pragma unroll
    for (int nt = 0; nt < 4; ++nt)
        #pragma unroll
        for (int j = 0; j < 4; ++j) acc[nt][j] = 0.f;

    const int arow = w * 16 + l16;
    const int aswz = (arow & 7) << 4;
    #pragma unroll
    for (int kt = 0; kt < 4; ++kt) {
        const int koff = kt * 64 + kg * 16;
        s16x8 ah = *(const s16x8*)((const char*)sxh + ((arow * 256 + koff) ^ aswz));
        s16x8 al = *(const s16x8*)((const char*)sxl + ((arow * 256 + koff) ^ aswz));
        #pragma unroll
        for (int nt = 0; nt < 4; ++nt) {
            const int c = nt * 16 + l16;
            const int wb = (c * 256 + koff) ^ ((c & 7) << 4);
            s16x8 bh = *(const s16x8*)((const char*)wth + wb);
            s16x8 bl = *(const s16x8*)((const char*)wtl + wb);
            acc[nt] = __builtin_amdgcn_mfma_f32_16x16x32_bf16(ah, bh, acc[nt], 0, 0, 0);
            acc[nt] = __builtin_amdgcn_mfma_f32_16x16x32_bf16(ah, bl, acc[nt], 0, 0, 0);
            acc[nt] = __builtin_amdgcn_mfma_f32_16x16x32_bf16(al, bh, acc[nt], 0, 0, 0);
        }
    }
    const int rbase = blk * 64 + w * 16 + kg * 4;
    #pragma unroll
    for (int reg = 0; reg < 4; ++reg) {
        int row = rbase + reg;
        quant_store_row(acc[0][reg], acc[1][reg], acc[2][reg], acc[3][reg],
                        row, l16, H8, scale);
    }
}

// ------------- per-bucket CSR build: atomic-ticket base, packed row ---------
// rowPack[node] = (start << 8) | deg   (deg max ~50 for this graph)
__global__ __launch_bounds__(256) void k_build(const unsigned int* __restrict__ bins,
                                               const int* __restrict__ bucketCursor,
                                               int* totalCursor,
                                               unsigned int* __restrict__ rowPack,
                                               float* __restrict__ dinv,
                                               int* __restrict__ csr_src) {
    __shared__ int cnt[128];
    __shared__ int ps[128];
    __shared__ int cur[128];
    __shared__ int gbS;
    const int b = blockIdx.x;
    const int t = threadIdx.x;
    const int bcnt = bucketCursor[b];
    const unsigned int* mybins = bins + (size_t)b * BCAP;

    if (t == 0) gbS = atomicAdd(totalCursor, bcnt);
    if (t < 128) cnt[t] = 0;
    __syncthreads();
    for (int i = t; i < bcnt; i += 256)
        atomicAdd(&cnt[mybins[i] >> 17], 1);
    __syncthreads();
    if (t < 128) ps[t] = cnt[t];
    __syncthreads();
    #pragma unroll
    for (int off = 1; off < 128; off <<= 1) {
        int x = (t >= off && t < 128) ? ps[t - off] : 0;
        __syncthreads();
        if (t < 128) ps[t] += x;
        __syncthreads();
    }
    const int gb = gbS;
    if (t < 128) {
        int excl = (t > 0) ? ps[t - 1] : 0;
        cur[t] = excl;
        int node = (b << 7) + t;
        if (node < N_NODES) {
            rowPack[node] = ((unsigned)(gb + excl) << 8) | (unsigned)cnt[t];
            dinv[node] = rsqrtf((float)(cnt[t] + 1));
        }
    }
    __syncthreads();
    for (int i = t; i < bcnt; i += 256) {
        unsigned w = mybins[i];
        int dl = w >> 17;
        int s = (int)(w & 0x1FFFFu);
        int p = atomicAdd(&cur[dl], 1);
        csr_src[gb + p] = s;
    }
}

// ------------------------------------------------------- GEMM2 (MFMA) -------
// bf16 input, UNSCALED quantized output (dinv applied in aggregate).
__global__ __launch_bounds__(256) void k_gemm2(const u16* __restrict__ Xb,
                                               const u16* __restrict__ w2pre,
                                               signed char* __restrict__ H8,
                                               float* __restrict__ scale) {
    __shared__ u16 sxb[64 * 64];
    __shared__ u16 wth[64 * 64];
    __shared__ u16 wtl[64 * 64];
    const int t = threadIdx.x;
    const int blk = blockIdx.x;

    {
        const u16x8* Xv = (const u16x8*)Xb;
        #pragma unroll
        for (int i = 0; i < 2; ++i) {
            int idx = i * 256 + t;
            int row = idx >> 3;
            int k0  = (idx & 7) << 3;
            int grow = blk * 64 + row;
            u16x8 v;
            #pragma unroll
            for (int j = 0; j < 8; ++j) v[j] = 0;
            if (grow < N_NODES) v = Xv[(size_t)grow * 8 + (idx & 7)];
            int byte = (row * 128 + k0 * 2) ^ ((row & 7) << 4);
            *(u16x8*)((char*)sxb + byte) = v;
        }
    }
    {
        const u16x8* G = (const u16x8*)w2pre;
        u16x8* Lh = (u16x8*)wth;
        u16x8* Ll = (u16x8*)wtl;
        #pragma unroll
        for (int i = 0; i < 2; ++i) Lh[i * 256 + t] = G[i * 256 + t];
        #pragma unroll
        for (int i = 0; i < 2; ++i) Ll[i * 256 + t] = G[512 + i * 256 + t];
    }
    __syncthreads();

    const int lane = t & 63;
    const int w    = t >> 6;
    const int l16  = lane & 15;
    const int kg   = lane >> 4;
    f32x4 acc[4];
    #pragma unroll
    for (int nt = 0; nt < 4; ++nt)
        #pragma unroll
        for (int j = 0; j < 4; ++j) acc[nt][j] = 0.f;

    const int arow = w * 16 + l16;
    const int aswz = (arow & 7) << 4;
    #pragma unroll
    for (int kt = 0; kt < 2; ++kt) {
        const int koff = kt * 64 + kg * 16;
        s16x8 a = *(const s16x8*)((const char*)sxb + ((arow * 128 + koff) ^ aswz));
        #pragma unroll
        for (int nt = 0; nt < 4; ++nt) {
            const int c = nt * 16 + l16;
            const int wb = (c * 128 + koff) ^ ((c & 7) << 4);
            s16x8 bh = *(const s16x8*)((const char*)wth + wb);
            s16x8 bl = *(const s16x8*)((const char*)wtl + wb);
            acc[nt] = __builtin_amdgcn_mfma_f32_16x16x32_bf16(a, bh, acc[nt], 0, 0, 0);
            acc[nt] = __builtin_amdgcn_mfma_f32_16x16x32_bf16(a, bl, acc[nt], 0, 0, 0);
        }
    }
    const int rbase = blk * 64 + w * 16 + kg * 4;
    #pragma unroll
    for (int reg = 0; reg < 4; ++reg) {
        int row = rbase + reg;
        quant_store_row(acc[0][reg], acc[1][reg], acc[2][reg], acc[3][reg],
                        row, l16, H8, scale);
    }
}

// ---------------------------------------------------------------- aggregate -
// One wave per node, int8 table, vector-path csr/scale/dinv loads with
// v_readlane broadcasts. Per-edge factor = scale[idx]*dinv[idx].
template <bool GELU>
__global__ __launch_bounds__(256) void k_aggregate(const signed char* __restrict__ hs8,
                                                   const float* __restrict__ scale,
                                                   const float* __restrict__ dinv,
                                                   const int* __restrict__ csr_src,
                                                   const unsigned int* __restrict__ rowPack,
                                                   const float* __restrict__ b,
                                                   void* __restrict__ outraw) {
    const int t = threadIdx.x;
    const int lane = t & 63;
    const int node = __builtin_amdgcn_readfirstlane(blockIdx.x * 4 + (t >> 6));
    const unsigned u = __builtin_amdgcn_readfirstlane(rowPack[node]);
    const int jS  = (int)(u >> 8);
    const int deg = (int)(u & 255u);
    const signed char* __restrict__ colp = hs8 + lane;

    const int l32 = lane & 31;
    int rr = csr_src[jS + l32];                      // coalesced vector load
    int myIdx = (l32 < deg) ? rr : N_NODES;          // zero row (scale 0)
    float myS = scale[myIdx] * dinv[myIdx];          // 4B gathers, L2-resident

    const float dn = dinv[node];
    float acc = (float)colp[(size_t)node << 6] * (scale[node] * dn);  // self

    signed char v[32];
    #pragma unroll
    for (int i = 0; i < 32; ++i) {
        int r = __builtin_amdgcn_readlane(myIdx, i);             // SGPR
        v[i] = colp[(size_t)(unsigned)r << 6];                   // saddr byte load
    }
    #pragma unroll
    for (int i = 0; i < 32; ++i) {
        float s = __uint_as_float(__builtin_amdgcn_readlane(__float_as_uint(myS), i));
        acc += (float)v[i] * s;
    }

    if (deg > 32) {   // rare tail
        for (int j = jS + 32; j < jS + deg; ++j) {
            int r = __builtin_amdgcn_readfirstlane(csr_src[j]);
            float s = __uint_as_float(__builtin_amdgcn_readfirstlane(
                          __float_as_uint(scale[r] * dinv[r])));
            acc += (float)colp[(size_t)(unsigned)r << 6] * s;
        }
    }

    float r = dn * acc + b[lane];
    if (GELU) {
        r = 0.5f * r * (1.0f + erff(r * 0.70710678118654752f));
        ((u16*)outraw)[((size_t)node << 6) + lane] = f2bf(r);
    } else {
        ((float*)outraw)[((size_t)node << 6) + lane] = r;
    }
}

// ---------------------------------------------------------------- launch ----
extern "C" void kernel_launch(void* const* d_in, const int* in_sizes, int n_in,
                              void* d_out, int out_size, void* d_ws, size_t ws_size,
                              hipStream_t stream) {
    const float* x  = (const float*)d_in[0];
    const int* edge = (const int*)d_in[1];           // [2, N_EDGES] int32
    const float* W1 = (const float*)d_in[2];
    const float* b1 = (const float*)d_in[3];
    const float* W2 = (const float*)d_in[4];
    const float* b2 = (const float*)d_in[5];
    float* out = (float*)d_out;                      // [N_NODES, 64] fp32

    const int* src = edge;
    const int* dst = edge + N_EDGES;

    char* ws = (char*)d_ws;
    int*      bucketCursor = (int*)(ws);                  // 782 ints
    int*      totalCursor  = (int*)(ws + 4096);           // 1 int (pad 8192)
    unsigned* rowPack      = (unsigned*)(ws + 8192);      // N (pad 408576)
    float*    dinv         = (float*)(ws + 408576);       // NROWS (pad 808960)
    int*      csr_src      = (int*)(ws + 808960);         // E + 64 slack (ends 7209216)
    float*    scale1       = (float*)(ws + 7209216);      // NROWS (ends 7609344)
    float*    scale2       = (float*)(ws + 7609344);      // NROWS (ends 8009472)
    signed char* hs8a      = (signed char*)(ws + 8009472);   // NROWS*64 (ends 14411520)
    signed char* hs8b      = (signed char*)(ws + 14411520);  // NROWS*64 (ends 20813568)
    u16*      out1b        = (u16*)(ws + 20813568);       // NROWS*64 bf16 (ends 33617664)
    unsigned* bins         = (unsigned*)out1b;            // 8.13MB alias, dead before agg1
    u16*      w1pre        = (u16*)(ws + 33617664);       // 32 KB
    u16*      w2pre        = (u16*)(ws + 33650432);       // 16 KB

    const int nBlkAgg = N_NODES / 4;                      // 25000

    // 1. weight pre-split + cursor zeroing
    k_pre<<<32, 256, 0, stream>>>(W1, W2, w1pre, w2pre, bucketCursor, totalCursor, dinv);
    // 2. edge binning (8KB LDS, full occupancy)
    k_bin<<<NBINBLK, 256, 0, stream>>>(src, dst, bucketCursor, bins);
    // 3. GEMM1 (independent of CSR; unscaled int8 + scale)
    k_gemm1<<<NGEMMBLK, 256, 0, stream>>>(x, w1pre, hs8a, scale1);
    // 4. CSR build (ticket-based, packed row_start|deg)
    k_build<<<NBUK, 256, 0, stream>>>(bins, bucketCursor, totalCursor, rowPack, dinv, csr_src);
    // 5. aggregate layer 1 (+bias+GELU) -> bf16
    k_aggregate<true><<<nBlkAgg, 256, 0, stream>>>(hs8a, scale1, dinv, csr_src, rowPack, b1, out1b);
    // 6. GEMM2 -> int8+scale
    k_gemm2<<<NGEMMBLK, 256, 0, stream>>>(out1b, w2pre, hs8b, scale2);
    // 7. aggregate layer 2 (+bias) -> fp32 out
    k_aggregate<false><<<nBlkAgg, 256, 0, stream>>>(hs8b, scale2, dinv, csr_src, rowPack, b2, out);
}

// Round 19
// 160.895 us; speedup vs baseline: 1.0170x; 1.0170x over previous
//
#include <hip/hip_runtime.h>
#include <math.h>

#define N_NODES 100000
#define N_EDGES 1600000
#define NROWS 100032
#define NBUK 782          // dst>>7 -> 0..781 (128 nodes per bucket)
#define BCAP 2600         // entries per bucket region (mean 2046)
#define BINCHUNK 4096     // edges per bin block (256 thr x 16)
#define NBINBLK 391
#define NGEMMBLK 1563     // NROWS/64

typedef unsigned short u16;
typedef u16 u16x4 __attribute__((ext_vector_type(4)));
typedef u16 u16x8 __attribute__((ext_vector_type(8)));
typedef short s16x8 __attribute__((ext_vector_type(8)));
typedef float f32x4 __attribute__((ext_vector_type(4)));

__device__ __forceinline__ float bf2f(u16 u) {
    union { unsigned i; float f; } v; v.i = ((unsigned)u) << 16; return v.f;
}
__device__ __forceinline__ u16 f2bf(float f) {
    union { float f; unsigned i; } v; v.f = f;
    return (u16)((v.i + 0x7FFFu + ((v.i >> 16) & 1u)) >> 16);  // RNE
}

// ------------------------- pre: W split + cursor zeroing (one dispatch) -----
__global__ __launch_bounds__(256) void k_pre(const float* __restrict__ W1,
                                             const float* __restrict__ W2,
                                             u16* __restrict__ w1pre,
                                             u16* __restrict__ w2pre,
                                             int* __restrict__ bucketCursor,
                                             int* __restrict__ totalCursor,
                                             float* __restrict__ dinv) {
    const int t = threadIdx.x;
    const int b = blockIdx.x;
    if (b < 16) {
        #pragma unroll
        for (int half = 0; half < 2; ++half) {
            int e = b * 512 + half * 256 + t;   // e = k*64 + c
            int k = e >> 6, c = e & 63;
            float f = W1[e];
            u16 h = f2bf(f);
            u16 l = f2bf(f - bf2f(h));
            int byte = (c * 256 + k * 2) ^ ((c & 7) << 4);
            *(u16*)((char*)w1pre + byte) = h;
            *(u16*)((char*)w1pre + 16384 + byte) = l;
        }
    } else {
        int e = (b - 16) * 256 + t;
        int k = e >> 6, c = e & 63;
        float f = W2[e];
        u16 h = f2bf(f);
        u16 l = f2bf(f - bf2f(h));
        int byte = (c * 128 + k * 2) ^ ((c & 7) << 4);
        *(u16*)((char*)w2pre + byte) = h;
        *(u16*)((char*)w2pre + 8192 + byte) = l;
    }
    if (b == 0) {
        for (int i = t; i < NBUK; i += 256) bucketCursor[i] = 0;
        if (t == 0) { totalCursor[0] = 0; dinv[N_NODES] = 0.f; }
    }
}

// -------------------------------- quantized-row epilogue helper (device) ----
__device__ __forceinline__ void quant_store_row(float v0, float v1, float v2, float v3,
                                                int row, int l16,
                                                signed char* __restrict__ H8,
                                                float* __restrict__ scale) {
    float m = fmaxf(fmaxf(fabsf(v0), fabsf(v1)), fmaxf(fabsf(v2), fabsf(v3)));
    m = fmaxf(m, __shfl_xor(m, 1));
    m = fmaxf(m, __shfl_xor(m, 2));
    m = fmaxf(m, __shfl_xor(m, 4));
    m = fmaxf(m, __shfl_xor(m, 8));
    float inv = (m > 0.f) ? 127.f / m : 0.f;
    if (l16 == 0) scale[row] = m * (1.f / 127.f);
    size_t base = (size_t)row * 64 + l16;
    H8[base +  0] = (signed char)__float2int_rn(v0 * inv);
    H8[base + 16] = (signed char)__float2int_rn(v1 * inv);
    H8[base + 32] = (signed char)__float2int_rn(v2 * inv);
    H8[base + 48] = (signed char)__float2int_rn(v3 * inv);
}

// ------------------- fused: edge binning (blocks<391) + GEMM1 (rest) --------
// 32KB LDS (x hi/lo staging only; W fragments read straight from L1-resident
// w1pre, already in swizzled fragment layout) -> 5 blocks/CU for BOTH phases.
__global__ __launch_bounds__(256) void k_bin_gemm1(const int* __restrict__ src,
                                                   const int* __restrict__ dst,
                                                   int* bucketCursor,
                                                   unsigned int* __restrict__ bins,
                                                   const float* __restrict__ X,
                                                   const u16* __restrict__ w1pre,
                                                   signed char* __restrict__ H8,
                                                   float* __restrict__ scale) {
    __shared__ __align__(16) char smem[32768];
    const int t = threadIdx.x;

    if (blockIdx.x < NBINBLK) {
        // ---------------- bin part (8KB of smem) ----------------
        int* lcnt  = (int*)smem;
        int* lbase = (int*)(smem + 4096);
        for (int i = t; i < NBUK; i += 256) lcnt[i] = 0;
        __syncthreads();

        const int e0 = blockIdx.x * BINCHUNK + t * 16;
        int4 s4[4], d4[4];
        int bkt[16], rnk[16];
        const bool valid = e0 < N_EDGES;
        if (valid) {
            #pragma unroll
            for (int k = 0; k < 4; ++k) {
                s4[k] = *(const int4*)(src + e0 + 4 * k);
                d4[k] = *(const int4*)(dst + e0 + 4 * k);
            }
            #pragma unroll
            for (int k = 0; k < 4; ++k) {
                int dd[4] = { d4[k].x, d4[k].y, d4[k].z, d4[k].w };
                #pragma unroll
                for (int j = 0; j < 4; ++j) {
                    int b = dd[j] >> 7;
                    bkt[4 * k + j] = b;
                    rnk[4 * k + j] = atomicAdd(&lcnt[b], 1);
                }
            }
        }
        __syncthreads();
        for (int i = t; i < NBUK; i += 256)
            if (lcnt[i] > 0) lbase[i] = atomicAdd(&bucketCursor[i], lcnt[i]);
        __syncthreads();
        if (valid) {
            #pragma unroll
            for (int k = 0; k < 4; ++k) {
                int ss[4] = { s4[k].x, s4[k].y, s4[k].z, s4[k].w };
                int dd[4] = { d4[k].x, d4[k].y, d4[k].z, d4[k].w };
                #pragma unroll
                for (int j = 0; j < 4; ++j) {
                    int i = 4 * k + j;
                    unsigned w = ((unsigned)(dd[j] & 127) << 17) | (unsigned)ss[j];
                    bins[(size_t)bkt[i] * BCAP + lbase[bkt[i]] + rnk[i]] = w;
                }
            }
        }
        return;
    }

    // ---------------- gemm1 part ----------------
    u16* sxh = (u16*)smem;              // 16KB
    u16* sxl = (u16*)(smem + 16384);    // 16KB
    const int blk = blockIdx.x - NBINBLK;

    {   // stage x tile: 64 rows x 128 cols fp32 -> hi/lo bf16
        const float4* Xv = (const float4*)X;
        #pragma unroll
        for (int i = 0; i < 8; ++i) {
            int idx = i * 256 + t;
            int row = idx >> 5;
            int k4  = (idx & 31) << 2;
            int grow = blk * 64 + row;
            float4 v = make_float4(0.f, 0.f, 0.f, 0.f);
            if (grow < N_NODES) v = Xv[(size_t)grow * 32 + (idx & 31)];
            float f[4] = { v.x, v.y, v.z, v.w };
            u16x4 hv, lv;
            #pragma unroll
            for (int j = 0; j < 4; ++j) {
                u16 h = f2bf(f[j]);
                hv[j] = h;
                lv[j] = f2bf(f[j] - bf2f(h));
            }
            int byte = (row * 256 + k4 * 2) ^ ((row & 7) << 4);
            *(u16x4*)((char*)sxh + byte) = hv;
            *(u16x4*)((char*)sxl + byte) = lv;
        }
    }
    __syncthreads();

    const int lane = t & 63;
    const int w    = t >> 6;
    const int l16  = lane & 15;
    const int kg   = lane >> 4;
    f32x4 acc[4];
    #pragma unroll
    for (int nt = 0; nt < 4; ++nt)
        #pragma unroll
        for (int j = 0; j < 4; ++j) acc[nt][j] = 0.f;

    const int arow = w * 16 + l16;
    const int aswz = (arow & 7) << 4;
    const char* Wg = (const char*)w1pre;
    #pragma unroll
    for (int kt = 0; kt < 4; ++kt) {
        const int koff = kt * 64 + kg * 16;
        s16x8 ah = *(const s16x8*)((const char*)sxh + ((arow * 256 + koff) ^ aswz));
        s16x8 al = *(const s16x8*)((const char*)sxl + ((arow * 256 + koff) ^ aswz));
        #pragma unroll
        for (int nt = 0; nt < 4; ++nt) {
            const int c = nt * 16 + l16;
            const int wb = (c * 256 + koff) ^ ((c & 7) << 4);
            s16x8 bh = *(const s16x8*)(Wg + wb);            // L1-resident
            s16x8 bl = *(const s16x8*)(Wg + 16384 + wb);
            acc[nt] = __builtin_amdgcn_mfma_f32_16x16x32_bf16(ah, bh, acc[nt], 0, 0, 0);
            acc[nt] = __builtin_amdgcn_mfma_f32_16x16x32_bf16(ah, bl, acc[nt], 0, 0, 0);
            acc[nt] = __builtin_amdgcn_mfma_f32_16x16x32_bf16(al, bh, acc[nt], 0, 0, 0);
        }
    }
    const int rbase = blk * 64 + w * 16 + kg * 4;
    #pragma unroll
    for (int reg = 0; reg < 4; ++reg) {
        int row = rbase + reg;
        quant_store_row(acc[0][reg], acc[1][reg], acc[2][reg], acc[3][reg],
                        row, l16, H8, scale);
    }
}

// ------------- per-bucket CSR build: atomic-ticket base, packed row ---------
// rowPack[node] = (start << 8) | deg   (deg max ~50 for this graph)
__global__ __launch_bounds__(256) void k_build(const unsigned int* __restrict__ bins,
                                               const int* __restrict__ bucketCursor,
                                               int* totalCursor,
                                               unsigned int* __restrict__ rowPack,
                                               float* __restrict__ dinv,
                                               int* __restrict__ csr_src) {
    __shared__ int cnt[128];
    __shared__ int ps[128];
    __shared__ int cur[128];
    __shared__ int gbS;
    const int b = blockIdx.x;
    const int t = threadIdx.x;
    const int bcnt = bucketCursor[b];
    const unsigned int* mybins = bins + (size_t)b * BCAP;

    if (t == 0) gbS = atomicAdd(totalCursor, bcnt);
    if (t < 128) cnt[t] = 0;
    __syncthreads();
    for (int i = t; i < bcnt; i += 256)
        atomicAdd(&cnt[mybins[i] >> 17], 1);
    __syncthreads();
    if (t < 128) ps[t] = cnt[t];
    __syncthreads();
    #pragma unroll
    for (int off = 1; off < 128; off <<= 1) {
        int x = (t >= off && t < 128) ? ps[t - off] : 0;
        __syncthreads();
        if (t < 128) ps[t] += x;
        __syncthreads();
    }
    const int gb = gbS;
    if (t < 128) {
        int excl = (t > 0) ? ps[t - 1] : 0;
        cur[t] = excl;
        int node = (b << 7) + t;
        if (node < N_NODES) {
            rowPack[node] = ((unsigned)(gb + excl) << 8) | (unsigned)cnt[t];
            dinv[node] = rsqrtf((float)(cnt[t] + 1));
        }
    }
    __syncthreads();
    for (int i = t; i < bcnt; i += 256) {
        unsigned w = mybins[i];
        int dl = w >> 17;
        int s = (int)(w & 0x1FFFFu);
        int p = atomicAdd(&cur[dl], 1);
        csr_src[gb + p] = s;
    }
}

// ------------------------------------------------------- GEMM2 (MFMA) -------
// bf16 input; W2 fragments read straight from L1-resident w2pre; 8KB LDS.
__global__ __launch_bounds__(256) void k_gemm2(const u16* __restrict__ Xb,
                                               const u16* __restrict__ w2pre,
                                               signed char* __restrict__ H8,
                                               float* __restrict__ scale) {
    __shared__ u16 sxb[64 * 64];
    const int t = threadIdx.x;
    const int blk = blockIdx.x;

    {   // stage input tile 64x64 bf16
        const u16x8* Xv = (const u16x8*)Xb;
        #pragma unroll
        for (int i = 0; i < 2; ++i) {
            int idx = i * 256 + t;
            int row = idx >> 3;
            int k0  = (idx & 7) << 3;
            int grow = blk * 64 + row;
            u16x8 v;
            #pragma unroll
            for (int j = 0; j < 8; ++j) v[j] = 0;
            if (grow < N_NODES) v = Xv[(size_t)grow * 8 + (idx & 7)];
            int byte = (row * 128 + k0 * 2) ^ ((row & 7) << 4);
            *(u16x8*)((char*)sxb + byte) = v;
        }
    }
    __syncthreads();

    const int lane = t & 63;
    const int w    = t >> 6;
    const int l16  = lane & 15;
    const int kg   = lane >> 4;
    f32x4 acc[4];
    #pragma unroll
    for (int nt = 0; nt < 4; ++nt)
        #pragma unroll
        for (int j = 0; j < 4; ++j) acc[nt][j] = 0.f;

    const int arow = w * 16 + l16;
    const int aswz = (arow & 7) << 4;
    const char* Wg = (const char*)w2pre;
    #pragma unroll
    for (int kt = 0; kt < 2; ++kt) {
        const int koff = kt * 64 + kg * 16;
        s16x8 a = *(const s16x8*)((const char*)sxb + ((arow * 128 + koff) ^ aswz));
        #pragma unroll
        for (int nt = 0; nt < 4; ++nt) {
            const int c = nt * 16 + l16;
            const int wb = (c * 128 + koff) ^ ((c & 7) << 4);
            s16x8 bh = *(const s16x8*)(Wg + wb);
            s16x8 bl = *(const s16x8*)(Wg + 8192 + wb);
            acc[nt] = __builtin_amdgcn_mfma_f32_16x16x32_bf16(a, bh, acc[nt], 0, 0, 0);
            acc[nt] = __builtin_amdgcn_mfma_f32_16x16x32_bf16(a, bl, acc[nt], 0, 0, 0);
        }
    }
    const int rbase = blk * 64 + w * 16 + kg * 4;
    #pragma unroll
    for (int reg = 0; reg < 4; ++reg) {
        int row = rbase + reg;
        quant_store_row(acc[0][reg], acc[1][reg], acc[2][reg], acc[3][reg],
                        row, l16, H8, scale);
    }
}

// ---------------------------------------------------------------- aggregate -
// One wave per node, int8 table, vector-path csr/scale/dinv loads with
// v_readlane broadcasts. Per-edge factor = scale[idx]*dinv[idx].
template <bool GELU>
__global__ __launch_bounds__(256) void k_aggregate(const signed char* __restrict__ hs8,
                                                   const float* __restrict__ scale,
                                                   const float* __restrict__ dinv,
                                                   const int* __restrict__ csr_src,
                                                   const unsigned int* __restrict__ rowPack,
                                                   const float* __restrict__ b,
                                                   void* __restrict__ outraw) {
    const int t = threadIdx.x;
    const int lane = t & 63;
    const int node = __builtin_amdgcn_readfirstlane(blockIdx.x * 4 + (t >> 6));
    const unsigned u = __builtin_amdgcn_readfirstlane(rowPack[node]);
    const int jS  = (int)(u >> 8);
    const int deg = (int)(u & 255u);
    const signed char* __restrict__ colp = hs8 + lane;

    const int l32 = lane & 31;
    int rr = csr_src[jS + l32];                      // coalesced vector load
    int myIdx = (l32 < deg) ? rr : N_NODES;          // zero row (scale 0)
    float myS = scale[myIdx] * dinv[myIdx];          // 4B gathers, L2-resident

    const float dn = dinv[node];
    float acc = (float)colp[(size_t)node << 6] * (scale[node] * dn);  // self

    signed char v[32];
    #pragma unroll
    for (int i = 0; i < 32; ++i) {
        int r = __builtin_amdgcn_readlane(myIdx, i);             // SGPR
        v[i] = colp[(size_t)(unsigned)r << 6];                   // saddr byte load
    }
    #pragma unroll
    for (int i = 0; i < 32; ++i) {
        float s = __uint_as_float(__builtin_amdgcn_readlane(__float_as_uint(myS), i));
        acc += (float)v[i] * s;
    }

    if (deg > 32) {   // rare tail
        for (int j = jS + 32; j < jS + deg; ++j) {
            int r = __builtin_amdgcn_readfirstlane(csr_src[j]);
            float s = __uint_as_float(__builtin_amdgcn_readfirstlane(
                          __float_as_uint(scale[r] * dinv[r])));
            acc += (float)colp[(size_t)(unsigned)r << 6] * s;
        }
    }

    float r = dn * acc + b[lane];
    if (GELU) {
        r = 0.5f * r * (1.0f + erff(r * 0.70710678118654752f));
        ((u16*)outraw)[((size_t)node << 6) + lane] = f2bf(r);
    } else {
        ((float*)outraw)[((size_t)node << 6) + lane] = r;
    }
}

// ---------------------------------------------------------------- launch ----
extern "C" void kernel_launch(void* const* d_in, const int* in_sizes, int n_in,
                              void* d_out, int out_size, void* d_ws, size_t ws_size,
                              hipStream_t stream) {
    const float* x  = (const float*)d_in[0];
    const int* edge = (const int*)d_in[1];           // [2, N_EDGES] int32
    const float* W1 = (const float*)d_in[2];
    const float* b1 = (const float*)d_in[3];
    const float* W2 = (const float*)d_in[4];
    const float* b2 = (const float*)d_in[5];
    float* out = (float*)d_out;                      // [N_NODES, 64] fp32

    const int* src = edge;
    const int* dst = edge + N_EDGES;

    char* ws = (char*)d_ws;
    int*      bucketCursor = (int*)(ws);                  // 782 ints
    int*      totalCursor  = (int*)(ws + 4096);           // 1 int (pad 8192)
    unsigned* rowPack      = (unsigned*)(ws + 8192);      // N (pad 408576)
    float*    dinv         = (float*)(ws + 408576);       // NROWS (pad 808960)
    int*      csr_src      = (int*)(ws + 808960);         // E + 64 slack (ends 7209216)
    float*    scale1       = (float*)(ws + 7209216);      // NROWS (ends 7609344)
    float*    scale2       = (float*)(ws + 7609344);      // NROWS (ends 8009472)
    signed char* hs8a      = (signed char*)(ws + 8009472);   // NROWS*64 (ends 14411520)
    signed char* hs8b      = (signed char*)(ws + 14411520);  // NROWS*64 (ends 20813568)
    u16*      out1b        = (u16*)(ws + 20813568);       // NROWS*64 bf16 (ends 33617664)
    unsigned* bins         = (unsigned*)out1b;            // 8.13MB alias, dead before agg1
    u16*      w1pre        = (u16*)(ws + 33617664);       // 32 KB
    u16*      w2pre        = (u16*)(ws + 33650432);       // 16 KB

    const int nBlkAgg = N_NODES / 4;                      // 25000

    // 1. weight pre-split + cursor zeroing
    k_pre<<<32, 256, 0, stream>>>(W1, W2, w1pre, w2pre, bucketCursor, totalCursor, dinv);
    // 2. fused edge binning + GEMM1 (32KB LDS -> 5 blocks/CU both phases)
    k_bin_gemm1<<<NBINBLK + NGEMMBLK, 256, 0, stream>>>(src, dst, bucketCursor, bins,
                                                        x, w1pre, hs8a, scale1);
    // 3. CSR build (ticket-based, packed row_start|deg)
    k_build<<<NBUK, 256, 0, stream>>>(bins, bucketCursor, totalCursor, rowPack, dinv, csr_src);
    // 4. aggregate layer 1 (+bias+GELU) -> bf16
    k_aggregate<true><<<nBlkAgg, 256, 0, stream>>>(hs8a, scale1, dinv, csr_src, rowPack, b1, out1b);
    // 5. GEMM2 -> int8+scale
    k_gemm2<<<NGEMMBLK, 256, 0, stream>>>(out1b, w2pre, hs8b, scale2);
    // 6. aggregate layer 2 (+bias) -> fp32 out
    k_aggregate<false><<<nBlkAgg, 256, 0, stream>>>(hs8b, scale2, dinv, csr_src, rowPack, b2, out);
}

// Round 20
// 151.536 us; speedup vs baseline: 1.0799x; 1.0618x over previous
//
#include <hip/hip_runtime.h>
#include <math.h>

#define N_NODES 100000
#define N_EDGES 1600000
#define NROWS 100032
#define NBUK 782          // dst>>7 -> 0..781 (128 nodes per bucket)
#define BCAP 2600         // entries per bucket region (mean 2046)
#define BINCHUNK 4096     // edges per bin block (256 thr x 16)
#define NBINBLK 391
#define NGEMMBLK 1563     // NROWS/64

typedef unsigned short u16;
typedef u16 u16x4 __attribute__((ext_vector_type(4)));
typedef u16 u16x8 __attribute__((ext_vector_type(8)));
typedef short s16x8 __attribute__((ext_vector_type(8)));
typedef float f32x4 __attribute__((ext_vector_type(4)));

__device__ __forceinline__ float bf2f(u16 u) {
    union { unsigned i; float f; } v; v.i = ((unsigned)u) << 16; return v.f;
}
__device__ __forceinline__ u16 f2bf(float f) {
    union { float f; unsigned i; } v; v.f = f;
    return (u16)((v.i + 0x7FFFu + ((v.i >> 16) & 1u)) >> 16);  // RNE
}

// ------------------------- pre: W split + cursor zeroing (one dispatch) -----
__global__ __launch_bounds__(256) void k_pre(const float* __restrict__ W1,
                                             const float* __restrict__ W2,
                                             u16* __restrict__ w1pre,
                                             u16* __restrict__ w2pre,
                                             int* __restrict__ bucketCursor,
                                             int* __restrict__ totalCursor,
                                             float* __restrict__ dinv) {
    const int t = threadIdx.x;
    const int b = blockIdx.x;
    if (b < 16) {
        #pragma unroll
        for (int half = 0; half < 2; ++half) {
            int e = b * 512 + half * 256 + t;   // e = k*64 + c
            int k = e >> 6, c = e & 63;
            float f = W1[e];
            u16 h = f2bf(f);
            u16 l = f2bf(f - bf2f(h));
            int byte = (c * 256 + k * 2) ^ ((c & 7) << 4);
            *(u16*)((char*)w1pre + byte) = h;
            *(u16*)((char*)w1pre + 16384 + byte) = l;
        }
    } else {
        int e = (b - 16) * 256 + t;
        int k = e >> 6, c = e & 63;
        float f = W2[e];
        u16 h = f2bf(f);
        u16 l = f2bf(f - bf2f(h));
        int byte = (c * 128 + k * 2) ^ ((c & 7) << 4);
        *(u16*)((char*)w2pre + byte) = h;
        *(u16*)((char*)w2pre + 8192 + byte) = l;
    }
    if (b == 0) {
        for (int i = t; i < NBUK; i += 256) bucketCursor[i] = 0;
        if (t == 0) { totalCursor[0] = 0; dinv[N_NODES] = 0.f; }
    }
}

// -------------------------------- quantized-row epilogue helper (device) ----
__device__ __forceinline__ void quant_store_row(float v0, float v1, float v2, float v3,
                                                int row, int l16,
                                                signed char* __restrict__ H8,
                                                float* __restrict__ scale) {
    float m = fmaxf(fmaxf(fabsf(v0), fabsf(v1)), fmaxf(fabsf(v2), fabsf(v3)));
    m = fmaxf(m, __shfl_xor(m, 1));
    m = fmaxf(m, __shfl_xor(m, 2));
    m = fmaxf(m, __shfl_xor(m, 4));
    m = fmaxf(m, __shfl_xor(m, 8));
    float inv = (m > 0.f) ? 127.f / m : 0.f;
    if (l16 == 0) scale[row] = m * (1.f / 127.f);
    size_t base = (size_t)row * 64 + l16;
    H8[base +  0] = (signed char)__float2int_rn(v0 * inv);
    H8[base + 16] = (signed char)__float2int_rn(v1 * inv);
    H8[base + 32] = (signed char)__float2int_rn(v2 * inv);
    H8[base + 48] = (signed char)__float2int_rn(v3 * inv);
}

// ------------------- fused: edge binning (blocks<391) + GEMM1 (rest) --------
// r17 configuration (64KB LDS, W staged in LDS) — best measured.
__global__ __launch_bounds__(256) void k_bin_gemm1(const int* __restrict__ src,
                                                   const int* __restrict__ dst,
                                                   int* bucketCursor,
                                                   unsigned int* __restrict__ bins,
                                                   const float* __restrict__ X,
                                                   const u16* __restrict__ w1pre,
                                                   signed char* __restrict__ H8,
                                                   float* __restrict__ scale) {
    __shared__ __align__(16) char smem[65536];
    const int t = threadIdx.x;

    if (blockIdx.x < NBINBLK) {
        // ---------------- bin part ----------------
        int* lcnt  = (int*)smem;
        int* lbase = (int*)(smem + 4096);
        for (int i = t; i < NBUK; i += 256) lcnt[i] = 0;
        __syncthreads();

        const int e0 = blockIdx.x * BINCHUNK + t * 16;
        int4 s4[4], d4[4];
        int bkt[16], rnk[16];
        const bool valid = e0 < N_EDGES;
        if (valid) {
            #pragma unroll
            for (int k = 0; k < 4; ++k) {
                s4[k] = *(const int4*)(src + e0 + 4 * k);
                d4[k] = *(const int4*)(dst + e0 + 4 * k);
            }
            #pragma unroll
            for (int k = 0; k < 4; ++k) {
                int dd[4] = { d4[k].x, d4[k].y, d4[k].z, d4[k].w };
                #pragma unroll
                for (int j = 0; j < 4; ++j) {
                    int b = dd[j] >> 7;
                    bkt[4 * k + j] = b;
                    rnk[4 * k + j] = atomicAdd(&lcnt[b], 1);
                }
            }
        }
        __syncthreads();
        for (int i = t; i < NBUK; i += 256)
            if (lcnt[i] > 0) lbase[i] = atomicAdd(&bucketCursor[i], lcnt[i]);
        __syncthreads();
        if (valid) {
            #pragma unroll
            for (int k = 0; k < 4; ++k) {
                int ss[4] = { s4[k].x, s4[k].y, s4[k].z, s4[k].w };
                int dd[4] = { d4[k].x, d4[k].y, d4[k].z, d4[k].w };
                #pragma unroll
                for (int j = 0; j < 4; ++j) {
                    int i = 4 * k + j;
                    unsigned w = ((unsigned)(dd[j] & 127) << 17) | (unsigned)ss[j];
                    bins[(size_t)bkt[i] * BCAP + lbase[bkt[i]] + rnk[i]] = w;
                }
            }
        }
        return;
    }

    // ---------------- gemm1 part ----------------
    u16* sxh = (u16*)smem;
    u16* sxl = (u16*)(smem + 16384);
    u16* wth = (u16*)(smem + 32768);
    u16* wtl = (u16*)(smem + 49152);
    const int blk = blockIdx.x - NBINBLK;

    {
        const float4* Xv = (const float4*)X;
        #pragma unroll
        for (int i = 0; i < 8; ++i) {
            int idx = i * 256 + t;
            int row = idx >> 5;
            int k4  = (idx & 31) << 2;
            int grow = blk * 64 + row;
            float4 v = make_float4(0.f, 0.f, 0.f, 0.f);
            if (grow < N_NODES) v = Xv[(size_t)grow * 32 + (idx & 31)];
            float f[4] = { v.x, v.y, v.z, v.w };
            u16x4 hv, lv;
            #pragma unroll
            for (int j = 0; j < 4; ++j) {
                u16 h = f2bf(f[j]);
                hv[j] = h;
                lv[j] = f2bf(f[j] - bf2f(h));
            }
            int byte = (row * 256 + k4 * 2) ^ ((row & 7) << 4);
            *(u16x4*)((char*)sxh + byte) = hv;
            *(u16x4*)((char*)sxl + byte) = lv;
        }
    }
    {
        const u16x8* G = (const u16x8*)w1pre;
        u16x8* Lh = (u16x8*)wth;
        u16x8* Ll = (u16x8*)wtl;
        #pragma unroll
        for (int i = 0; i < 4; ++i) Lh[i * 256 + t] = G[i * 256 + t];
        #pragma unroll
        for (int i = 0; i < 4; ++i) Ll[i * 256 + t] = G[1024 + i * 256 + t];
    }
    __syncthreads();

    const int lane = t & 63;
    const int w    = t >> 6;
    const int l16  = lane & 15;
    const int kg   = lane >> 4;
    f32x4 acc[4];
    #pragma unroll
    for (int nt = 0; nt < 4; ++nt)
        #pragma unroll
        for (int j = 0; j < 4; ++j) acc[nt][j] = 0.f;

    const int arow = w * 16 + l16;
    const int aswz = (arow & 7) << 4;
    #pragma unroll
    for (int kt = 0; kt < 4; ++kt) {
        const int koff = kt * 64 + kg * 16;
        s16x8 ah = *(const s16x8*)((const char*)sxh + ((arow * 256 + koff) ^ aswz));
        s16x8 al = *(const s16x8*)((const char*)sxl + ((arow * 256 + koff) ^ aswz));
        #pragma unroll
        for (int nt = 0; nt < 4; ++nt) {
            const int c = nt * 16 + l16;
            const int wb = (c * 256 + koff) ^ ((c & 7) << 4);
            s16x8 bh = *(const s16x8*)((const char*)wth + wb);
            s16x8 bl = *(const s16x8*)((const char*)wtl + wb);
            acc[nt] = __builtin_amdgcn_mfma_f32_16x16x32_bf16(ah, bh, acc[nt], 0, 0, 0);
            acc[nt] = __builtin_amdgcn_mfma_f32_16x16x32_bf16(ah, bl, acc[nt], 0, 0, 0);
            acc[nt] = __builtin_amdgcn_mfma_f32_16x16x32_bf16(al, bh, acc[nt], 0, 0, 0);
        }
    }
    const int rbase = blk * 64 + w * 16 + kg * 4;
    #pragma unroll
    for (int reg = 0; reg < 4; ++reg) {
        int row = rbase + reg;
        quant_store_row(acc[0][reg], acc[1][reg], acc[2][reg], acc[3][reg],
                        row, l16, H8, scale);
    }
}

// ------------- per-bucket CSR build: atomic-ticket base, packed row ---------
__global__ __launch_bounds__(256) void k_build(const unsigned int* __restrict__ bins,
                                               const int* __restrict__ bucketCursor,
                                               int* totalCursor,
                                               unsigned int* __restrict__ rowPack,
                                               float* __restrict__ dinv,
                                               int* __restrict__ csr_src) {
    __shared__ int cnt[128];
    __shared__ int ps[128];
    __shared__ int cur[128];
    __shared__ int gbS;
    const int b = blockIdx.x;
    const int t = threadIdx.x;
    const int bcnt = bucketCursor[b];
    const unsigned int* mybins = bins + (size_t)b * BCAP;

    if (t == 0) gbS = atomicAdd(totalCursor, bcnt);
    if (t < 128) cnt[t] = 0;
    __syncthreads();
    for (int i = t; i < bcnt; i += 256)
        atomicAdd(&cnt[mybins[i] >> 17], 1);
    __syncthreads();
    if (t < 128) ps[t] = cnt[t];
    __syncthreads();
    #pragma unroll
    for (int off = 1; off < 128; off <<= 1) {
        int x = (t >= off && t < 128) ? ps[t - off] : 0;
        __syncthreads();
        if (t < 128) ps[t] += x;
        __syncthreads();
    }
    const int gb = gbS;
    if (t < 128) {
        int excl = (t > 0) ? ps[t - 1] : 0;
        cur[t] = excl;
        int node = (b << 7) + t;
        if (node < N_NODES) {
            rowPack[node] = ((unsigned)(gb + excl) << 8) | (unsigned)cnt[t];
            dinv[node] = rsqrtf((float)(cnt[t] + 1));
        }
    }
    __syncthreads();
    for (int i = t; i < bcnt; i += 256) {
        unsigned w = mybins[i];
        int dl = w >> 17;
        int s = (int)(w & 0x1FFFFu);
        int p = atomicAdd(&cur[dl], 1);
        csr_src[gb + p] = s;
    }
}

// ------------------------------------------------------- GEMM2 (MFMA) -------
__global__ __launch_bounds__(256) void k_gemm2(const u16* __restrict__ Xb,
                                               const u16* __restrict__ w2pre,
                                               signed char* __restrict__ H8,
                                               float* __restrict__ scale) {
    __shared__ u16 sxb[64 * 64];
    __shared__ u16 wth[64 * 64];
    __shared__ u16 wtl[64 * 64];
    const int t = threadIdx.x;
    const int blk = blockIdx.x;

    {
        const u16x8* Xv = (const u16x8*)Xb;
        #pragma unroll
        for (int i = 0; i < 2; ++i) {
            int idx = i * 256 + t;
            int row = idx >> 3;
            int k0  = (idx & 7) << 3;
            int grow = blk * 64 + row;
            u16x8 v;
            #pragma unroll
            for (int j = 0; j < 8; ++j) v[j] = 0;
            if (grow < N_NODES) v = Xv[(size_t)grow * 8 + (idx & 7)];
            int byte = (row * 128 + k0 * 2) ^ ((row & 7) << 4);
            *(u16x8*)((char*)sxb + byte) = v;
        }
    }
    {
        const u16x8* G = (const u16x8*)w2pre;
        u16x8* Lh = (u16x8*)wth;
        u16x8* Ll = (u16x8*)wtl;
        #pragma unroll
        for (int i = 0; i < 2; ++i) Lh[i * 256 + t] = G[i * 256 + t];
        #pragma unroll
        for (int i = 0; i < 2; ++i) Ll[i * 256 + t] = G[512 + i * 256 + t];
    }
    __syncthreads();

    const int lane = t & 63;
    const int w    = t >> 6;
    const int l16  = lane & 15;
    const int kg   = lane >> 4;
    f32x4 acc[4];
    #pragma unroll
    for (int nt = 0; nt < 4; ++nt)
        #pragma unroll
        for (int j = 0; j < 4; ++j) acc[nt][j] = 0.f;

    const int arow = w * 16 + l16;
    const int aswz = (arow & 7) << 4;
    #pragma unroll
    for (int kt = 0; kt < 2; ++kt) {
        const int koff = kt * 64 + kg * 16;
        s16x8 a = *(const s16x8*)((const char*)sxb + ((arow * 128 + koff) ^ aswz));
        #pragma unroll
        for (int nt = 0; nt < 4; ++nt) {
            const int c = nt * 16 + l16;
            const int wb = (c * 128 + koff) ^ ((c & 7) << 4);
            s16x8 bh = *(const s16x8*)((const char*)wth + wb);
            s16x8 bl = *(const s16x8*)((const char*)wtl + wb);
            acc[nt] = __builtin_amdgcn_mfma_f32_16x16x32_bf16(a, bh, acc[nt], 0, 0, 0);
            acc[nt] = __builtin_amdgcn_mfma_f32_16x16x32_bf16(a, bl, acc[nt], 0, 0, 0);
        }
    }
    const int rbase = blk * 64 + w * 16 + kg * 4;
    #pragma unroll
    for (int reg = 0; reg < 4; ++reg) {
        int row = rbase + reg;
        quant_store_row(acc[0][reg], acc[1][reg], acc[2][reg], acc[3][reg],
                        row, l16, H8, scale);
    }
}

// ------------------------------------- tiered gather window (device) --------
template <int N>
__device__ __forceinline__ void gather_tier(const signed char* __restrict__ colp,
                                            int myIdx, float myS, float& acc) {
    signed char v[N];
    #pragma unroll
    for (int i = 0; i < N; ++i) {
        int r = __builtin_amdgcn_readlane(myIdx, i);             // SGPR
        v[i] = colp[(size_t)(unsigned)r << 6];                   // saddr byte load
    }
    #pragma unroll
    for (int i = 0; i < N; ++i) {
        float s = __uint_as_float(__builtin_amdgcn_readlane(__float_as_uint(myS), i));
        acc += (float)v[i] * s;
    }
}

// ---------------------------------------------------------------- aggregate -
// One wave per node, int8 table, vector-path csr/scale/dinv + v_readlane
// broadcasts. Degree-TIERED window (16/24/32, wave-uniform branch): mean
// issued edges ~19.8 instead of 32. Dropped slots were exact +0.0 -> results
// bitwise identical to the 32-window version.
template <bool GELU>
__global__ __launch_bounds__(256) void k_aggregate(const signed char* __restrict__ hs8,
                                                   const float* __restrict__ scale,
                                                   const float* __restrict__ dinv,
                                                   const int* __restrict__ csr_src,
                                                   const unsigned int* __restrict__ rowPack,
                                                   const float* __restrict__ b,
                                                   void* __restrict__ outraw) {
    const int t = threadIdx.x;
    const int lane = t & 63;
    const int node = __builtin_amdgcn_readfirstlane(blockIdx.x * 4 + (t >> 6));
    const unsigned u = __builtin_amdgcn_readfirstlane(rowPack[node]);
    const int jS  = (int)(u >> 8);
    const int deg = (int)(u & 255u);
    const signed char* __restrict__ colp = hs8 + lane;

    const int l32 = lane & 31;
    int rr = csr_src[jS + l32];                      // coalesced vector load
    int myIdx = (l32 < deg) ? rr : N_NODES;          // zero row (scale 0)
    float myS = scale[myIdx] * dinv[myIdx];          // 4B gathers, L2-resident

    const float dn = dinv[node];
    float acc = (float)colp[(size_t)node << 6] * (scale[node] * dn);  // self

    if (deg <= 16) {
        gather_tier<16>(colp, myIdx, myS, acc);
    } else if (deg <= 24) {
        gather_tier<24>(colp, myIdx, myS, acc);
    } else {
        gather_tier<32>(colp, myIdx, myS, acc);
        if (deg > 32) {   // rare tail
            for (int j = jS + 32; j < jS + deg; ++j) {
                int r = __builtin_amdgcn_readfirstlane(csr_src[j]);
                float s = __uint_as_float(__builtin_amdgcn_readfirstlane(
                              __float_as_uint(scale[r] * dinv[r])));
                acc += (float)colp[(size_t)(unsigned)r << 6] * s;
            }
        }
    }

    float r = dn * acc + b[lane];
    if (GELU) {
        r = 0.5f * r * (1.0f + erff(r * 0.70710678118654752f));
        ((u16*)outraw)[((size_t)node << 6) + lane] = f2bf(r);
    } else {
        ((float*)outraw)[((size_t)node << 6) + lane] = r;
    }
}

// ---------------------------------------------------------------- launch ----
extern "C" void kernel_launch(void* const* d_in, const int* in_sizes, int n_in,
                              void* d_out, int out_size, void* d_ws, size_t ws_size,
                              hipStream_t stream) {
    const float* x  = (const float*)d_in[0];
    const int* edge = (const int*)d_in[1];           // [2, N_EDGES] int32
    const float* W1 = (const float*)d_in[2];
    const float* b1 = (const float*)d_in[3];
    const float* W2 = (const float*)d_in[4];
    const float* b2 = (const float*)d_in[5];
    float* out = (float*)d_out;                      // [N_NODES, 64] fp32

    const int* src = edge;
    const int* dst = edge + N_EDGES;

    char* ws = (char*)d_ws;
    int*      bucketCursor = (int*)(ws);                  // 782 ints
    int*      totalCursor  = (int*)(ws + 4096);           // 1 int (pad 8192)
    unsigned* rowPack      = (unsigned*)(ws + 8192);      // N (pad 408576)
    float*    dinv         = (float*)(ws + 408576);       // NROWS (pad 808960)
    int*      csr_src      = (int*)(ws + 808960);         // E + 64 slack (ends 7209216)
    float*    scale1       = (float*)(ws + 7209216);      // NROWS (ends 7609344)
    float*    scale2       = (float*)(ws + 7609344);      // NROWS (ends 8009472)
    signed char* hs8a      = (signed char*)(ws + 8009472);   // NROWS*64 (ends 14411520)
    signed char* hs8b      = (signed char*)(ws + 14411520);  // NROWS*64 (ends 20813568)
    u16*      out1b        = (u16*)(ws + 20813568);       // NROWS*64 bf16 (ends 33617664)
    unsigned* bins         = (unsigned*)out1b;            // 8.13MB alias, dead before agg1
    u16*      w1pre        = (u16*)(ws + 33617664);       // 32 KB
    u16*      w2pre        = (u16*)(ws + 33650432);       // 16 KB

    const int nBlkAgg = N_NODES / 4;                      // 25000

    // 1. weight pre-split + cursor zeroing
    k_pre<<<32, 256, 0, stream>>>(W1, W2, w1pre, w2pre, bucketCursor, totalCursor, dinv);
    // 2. fused edge binning + GEMM1 (r17 config)
    k_bin_gemm1<<<NBINBLK + NGEMMBLK, 256, 0, stream>>>(src, dst, bucketCursor, bins,
                                                        x, w1pre, hs8a, scale1);
    // 3. CSR build (ticket-based, packed row_start|deg)
    k_build<<<NBUK, 256, 0, stream>>>(bins, bucketCursor, totalCursor, rowPack, dinv, csr_src);
    // 4. aggregate layer 1 (+bias+GELU) -> bf16
    k_aggregate<true><<<nBlkAgg, 256, 0, stream>>>(hs8a, scale1, dinv, csr_src, rowPack, b1, out1b);
    // 5. GEMM2 -> int8+scale
    k_gemm2<<<NGEMMBLK, 256, 0, stream>>>(out1b, w2pre, hs8b, scale2);
    // 6. aggregate layer 2 (+bias) -> fp32 out
    k_aggregate<false><<<nBlkAgg, 256, 0, stream>>>(hs8b, scale2, dinv, csr_src, rowPack, b2, out);
}

// Round 22
// 147.837 us; speedup vs baseline: 1.1069x; 1.0250x over previous
//
#include <hip/hip_runtime.h>
#include <math.h>

#define N_NODES 100000
#define N_EDGES 1600000
#define NROWS 100032
#define NBUK 782          // dst>>7 -> 0..781 (128 nodes per bucket)
#define BCAP 2600         // entries per bucket region (mean 2046)
#define BINCHUNK 4096     // edges per bin block (256 thr x 16)
#define NBINBLK 391
#define NGEMMBLK 1563     // NROWS/64

typedef unsigned short u16;
typedef u16 u16x4 __attribute__((ext_vector_type(4)));
typedef u16 u16x8 __attribute__((ext_vector_type(8)));
typedef short s16x8 __attribute__((ext_vector_type(8)));
typedef float f32x4 __attribute__((ext_vector_type(4)));

__device__ __forceinline__ float bf2f(u16 u) {
    union { unsigned i; float f; } v; v.i = ((unsigned)u) << 16; return v.f;
}
__device__ __forceinline__ u16 f2bf(float f) {
    union { float f; unsigned i; } v; v.f = f;
    return (u16)((v.i + 0x7FFFu + ((v.i >> 16) & 1u)) >> 16);  // RNE
}

// ------------------------- pre: W split + cursor zeroing (one dispatch) -----
__global__ __launch_bounds__(256) void k_pre(const float* __restrict__ W1,
                                             const float* __restrict__ W2,
                                             u16* __restrict__ w1pre,
                                             u16* __restrict__ w2pre,
                                             int* __restrict__ bucketCursor,
                                             int* __restrict__ totalCursor,
                                             float* __restrict__ dinv) {
    const int t = threadIdx.x;
    const int b = blockIdx.x;
    if (b < 16) {
        #pragma unroll
        for (int half = 0; half < 2; ++half) {
            int e = b * 512 + half * 256 + t;   // e = k*64 + c
            int k = e >> 6, c = e & 63;
            float f = W1[e];
            u16 h = f2bf(f);
            u16 l = f2bf(f - bf2f(h));
            int byte = (c * 256 + k * 2) ^ ((c & 7) << 4);
            *(u16*)((char*)w1pre + byte) = h;
            *(u16*)((char*)w1pre + 16384 + byte) = l;
        }
    } else {
        int e = (b - 16) * 256 + t;
        int k = e >> 6, c = e & 63;
        float f = W2[e];
        u16 h = f2bf(f);
        u16 l = f2bf(f - bf2f(h));
        int byte = (c * 128 + k * 2) ^ ((c & 7) << 4);
        *(u16*)((char*)w2pre + byte) = h;
        *(u16*)((char*)w2pre + 8192 + byte) = l;
    }
    if (b == 0) {
        for (int i = t; i < NBUK; i += 256) bucketCursor[i] = 0;
        if (t == 0) { totalCursor[0] = 0; dinv[N_NODES] = 0.f; }
    }
}

// -------------------------------- quantized-row epilogue helper (device) ----
__device__ __forceinline__ void quant_store_row(float v0, float v1, float v2, float v3,
                                                int row, int l16,
                                                signed char* __restrict__ H8,
                                                float* __restrict__ scale) {
    float m = fmaxf(fmaxf(fabsf(v0), fabsf(v1)), fmaxf(fabsf(v2), fabsf(v3)));
    m = fmaxf(m, __shfl_xor(m, 1));
    m = fmaxf(m, __shfl_xor(m, 2));
    m = fmaxf(m, __shfl_xor(m, 4));
    m = fmaxf(m, __shfl_xor(m, 8));
    float inv = (m > 0.f) ? 127.f / m : 0.f;
    if (l16 == 0) scale[row] = m * (1.f / 127.f);
    size_t base = (size_t)row * 64 + l16;
    H8[base +  0] = (signed char)__float2int_rn(v0 * inv);
    H8[base + 16] = (signed char)__float2int_rn(v1 * inv);
    H8[base + 32] = (signed char)__float2int_rn(v2 * inv);
    H8[base + 48] = (signed char)__float2int_rn(v3 * inv);
}

// ------------------- fused: edge binning (blocks<391) + GEMM1 (rest) --------
// 48KB LDS: x staged in K=64 HALVES (8KB hi + 8KB lo) + W full (32KB)
// -> 3 blocks/CU for both phases (was 2 at 64KB).
__global__ __launch_bounds__(256) void k_bin_gemm1(const int* __restrict__ src,
                                                   const int* __restrict__ dst,
                                                   int* bucketCursor,
                                                   unsigned int* __restrict__ bins,
                                                   const float* __restrict__ X,
                                                   const u16* __restrict__ w1pre,
                                                   signed char* __restrict__ H8,
                                                   float* __restrict__ scale) {
    __shared__ __align__(16) char smem[49152];
    const int t = threadIdx.x;

    if (blockIdx.x < NBINBLK) {
        // ---------------- bin part (8KB of smem) ----------------
        int* lcnt  = (int*)smem;
        int* lbase = (int*)(smem + 4096);
        for (int i = t; i < NBUK; i += 256) lcnt[i] = 0;
        __syncthreads();

        const int e0 = blockIdx.x * BINCHUNK + t * 16;
        int4 s4[4], d4[4];
        int bkt[16], rnk[16];
        const bool valid = e0 < N_EDGES;
        if (valid) {
            #pragma unroll
            for (int k = 0; k < 4; ++k) {
                s4[k] = *(const int4*)(src + e0 + 4 * k);
                d4[k] = *(const int4*)(dst + e0 + 4 * k);
            }
            #pragma unroll
            for (int k = 0; k < 4; ++k) {
                int dd[4] = { d4[k].x, d4[k].y, d4[k].z, d4[k].w };
                #pragma unroll
                for (int j = 0; j < 4; ++j) {
                    int b = dd[j] >> 7;
                    bkt[4 * k + j] = b;
                    rnk[4 * k + j] = atomicAdd(&lcnt[b], 1);
                }
            }
        }
        __syncthreads();
        for (int i = t; i < NBUK; i += 256)
            if (lcnt[i] > 0) lbase[i] = atomicAdd(&bucketCursor[i], lcnt[i]);
        __syncthreads();
        if (valid) {
            #pragma unroll
            for (int k = 0; k < 4; ++k) {
                int ss[4] = { s4[k].x, s4[k].y, s4[k].z, s4[k].w };
                int dd[4] = { d4[k].x, d4[k].y, d4[k].z, d4[k].w };
                #pragma unroll
                for (int j = 0; j < 4; ++j) {
                    int i = 4 * k + j;
                    unsigned w = ((unsigned)(dd[j] & 127) << 17) | (unsigned)ss[j];
                    bins[(size_t)bkt[i] * BCAP + lbase[bkt[i]] + rnk[i]] = w;
                }
            }
        }
        return;
    }

    // ---------------- gemm1 part ----------------
    u16* sxh = (u16*)smem;              //  8KB: 64 rows x 64 k (current half)
    u16* sxl = (u16*)(smem +  8192);    //  8KB
    u16* wth = (u16*)(smem + 16384);    // 16KB: full W hi
    u16* wtl = (u16*)(smem + 32768);    // 16KB: full W lo
    const int blk = blockIdx.x - NBINBLK;

    {   // stage pre-split W1 (pure 16B copy, layout already swizzled)
        const u16x8* G = (const u16x8*)w1pre;
        u16x8* Lh = (u16x8*)wth;
        u16x8* Ll = (u16x8*)wtl;
        #pragma unroll
        for (int i = 0; i < 4; ++i) Lh[i * 256 + t] = G[i * 256 + t];
        #pragma unroll
        for (int i = 0; i < 4; ++i) Ll[i * 256 + t] = G[1024 + i * 256 + t];
    }

    const int lane = t & 63;
    const int w    = t >> 6;
    const int l16  = lane & 15;
    const int kg   = lane >> 4;
    f32x4 acc[4];
    #pragma unroll
    for (int nt = 0; nt < 4; ++nt)
        #pragma unroll
        for (int j = 0; j < 4; ++j) acc[nt][j] = 0.f;

    const int arow = w * 16 + l16;
    const int aswz = (arow & 7) << 4;
    const float4* Xv = (const float4*)X;

    #pragma unroll
    for (int kh = 0; kh < 2; ++kh) {
        if (kh) __syncthreads();   // protect previous half's reads
        // stage x half: 64 rows x 64 cols fp32 -> hi/lo bf16 (1024 float4)
        #pragma unroll
        for (int i = 0; i < 4; ++i) {
            int idx = i * 256 + t;
            int row = idx >> 4;              // 16 float4 per row
            int c4  = idx & 15;
            int grow = blk * 64 + row;
            float4 v = make_float4(0.f, 0.f, 0.f, 0.f);
            if (grow < N_NODES) v = Xv[(size_t)grow * 32 + kh * 16 + c4];
            float f[4] = { v.x, v.y, v.z, v.w };
            u16x4 hv, lv;
            #pragma unroll
            for (int j = 0; j < 4; ++j) {
                u16 h = f2bf(f[j]);
                hv[j] = h;
                lv[j] = f2bf(f[j] - bf2f(h));
            }
            int byte = (row * 128 + c4 * 8) ^ ((row & 7) << 4);
            *(u16x4*)((char*)sxh + byte) = hv;
            *(u16x4*)((char*)sxl + byte) = lv;
        }
        __syncthreads();

        #pragma unroll
        for (int kt = 0; kt < 2; ++kt) {
            const int koffA = kt * 64 + kg * 16;            // local (0..127)
            const int koffW = kh * 128 + kt * 64 + kg * 16; // global (0..255)
            s16x8 ah = *(const s16x8*)((const char*)sxh + ((arow * 128 + koffA) ^ aswz));
            s16x8 al = *(const s16x8*)((const char*)sxl + ((arow * 128 + koffA) ^ aswz));
            #pragma unroll
            for (int nt = 0; nt < 4; ++nt) {
                const int c = nt * 16 + l16;
                const int wb = (c * 256 + koffW) ^ ((c & 7) << 4);
                s16x8 bh = *(const s16x8*)((const char*)wth + wb);
                s16x8 bl = *(const s16x8*)((const char*)wtl + wb);
                acc[nt] = __builtin_amdgcn_mfma_f32_16x16x32_bf16(ah, bh, acc[nt], 0, 0, 0);
                acc[nt] = __builtin_amdgcn_mfma_f32_16x16x32_bf16(ah, bl, acc[nt], 0, 0, 0);
                acc[nt] = __builtin_amdgcn_mfma_f32_16x16x32_bf16(al, bh, acc[nt], 0, 0, 0);
            }
        }
    }

    const int rbase = blk * 64 + w * 16 + kg * 4;
    #pragma unroll
    for (int reg = 0; reg < 4; ++reg) {
        int row = rbase + reg;
        quant_store_row(acc[0][reg], acc[1][reg], acc[2][reg], acc[3][reg],
                        row, l16, H8, scale);
    }
}

// ------------- per-bucket CSR build: atomic-ticket base, packed row ---------
__global__ __launch_bounds__(256) void k_build(const unsigned int* __restrict__ bins,
                                               const int* __restrict__ bucketCursor,
                                               int* totalCursor,
                                               unsigned int* __restrict__ rowPack,
                                               float* __restrict__ dinv,
                                               int* __restrict__ csr_src) {
    __shared__ int cnt[128];
    __shared__ int ps[128];
    __shared__ int cur[128];
    __shared__ int gbS;
    const int b = blockIdx.x;
    const int t = threadIdx.x;
    const int bcnt = bucketCursor[b];
    const unsigned int* mybins = bins + (size_t)b * BCAP;

    if (t == 0) gbS = atomicAdd(totalCursor, bcnt);
    if (t < 128) cnt[t] = 0;
    __syncthreads();
    for (int i = t; i < bcnt; i += 256)
        atomicAdd(&cnt[mybins[i] >> 17], 1);
    __syncthreads();
    if (t < 128) ps[t] = cnt[t];
    __syncthreads();
    #pragma unroll
    for (int off = 1; off < 128; off <<= 1) {
        int x = (t >= off && t < 128) ? ps[t - off] : 0;
        __syncthreads();
        if (t < 128) ps[t] += x;
        __syncthreads();
    }
    const int gb = gbS;
    if (t < 128) {
        int excl = (t > 0) ? ps[t - 1] : 0;
        cur[t] = excl;
        int node = (b << 7) + t;
        if (node < N_NODES) {
            rowPack[node] = ((unsigned)(gb + excl) << 8) | (unsigned)cnt[t];
            dinv[node] = rsqrtf((float)(cnt[t] + 1));
        }
    }
    __syncthreads();
    for (int i = t; i < bcnt; i += 256) {
        unsigned w = mybins[i];
        int dl = w >> 17;
        int s = (int)(w & 0x1FFFFu);
        int p = atomicAdd(&cur[dl], 1);
        csr_src[gb + p] = s;
    }
}

// ------------------------------------------------------- GEMM2 (MFMA) -------
__global__ __launch_bounds__(256) void k_gemm2(const u16* __restrict__ Xb,
                                               const u16* __restrict__ w2pre,
                                               signed char* __restrict__ H8,
                                               float* __restrict__ scale) {
    __shared__ u16 sxb[64 * 64];
    __shared__ u16 wth[64 * 64];
    __shared__ u16 wtl[64 * 64];
    const int t = threadIdx.x;
    const int blk = blockIdx.x;

    {
        const u16x8* Xv = (const u16x8*)Xb;
        #pragma unroll
        for (int i = 0; i < 2; ++i) {
            int idx = i * 256 + t;
            int row = idx >> 3;
            int k0  = (idx & 7) << 3;
            int grow = blk * 64 + row;
            u16x8 v;
            #pragma unroll
            for (int j = 0; j < 8; ++j) v[j] = 0;
            if (grow < N_NODES) v = Xv[(size_t)grow * 8 + (idx & 7)];
            int byte = (row * 128 + k0 * 2) ^ ((row & 7) << 4);
            *(u16x8*)((char*)sxb + byte) = v;
        }
    }
    {
        const u16x8* G = (const u16x8*)w2pre;
        u16x8* Lh = (u16x8*)wth;
        u16x8* Ll = (u16x8*)wtl;
        #pragma unroll
        for (int i = 0; i < 2; ++i) Lh[i * 256 + t] = G[i * 256 + t];
        #pragma unroll
        for (int i = 0; i < 2; ++i) Ll[i * 256 + t] = G[512 + i * 256 + t];
    }
    __syncthreads();

    const int lane = t & 63;
    const int w    = t >> 6;
    const int l16  = lane & 15;
    const int kg   = lane >> 4;
    f32x4 acc[4];
    #pragma unroll
    for (int nt = 0; nt < 4; ++nt)
        #pragma unroll
        for (int j = 0; j < 4; ++j) acc[nt][j] = 0.f;

    const int arow = w * 16 + l16;
    const int aswz = (arow & 7) << 4;
    #pragma unroll
    for (int kt = 0; kt < 2; ++kt) {
        const int koff = kt * 64 + kg * 16;
        s16x8 a = *(const s16x8*)((const char*)sxb + ((arow * 128 + koff) ^ aswz));
        #pragma unroll
        for (int nt = 0; nt < 4; ++nt) {
            const int c = nt * 16 + l16;
            const int wb = (c * 128 + koff) ^ ((c & 7) << 4);
            s16x8 bh = *(const s16x8*)((const char*)wth + wb);
            s16x8 bl = *(const s16x8*)((const char*)wtl + wb);
            acc[nt] = __builtin_amdgcn_mfma_f32_16x16x32_bf16(a, bh, acc[nt], 0, 0, 0);
            acc[nt] = __builtin_amdgcn_mfma_f32_16x16x32_bf16(a, bl, acc[nt], 0, 0, 0);
        }
    }
    const int rbase = blk * 64 + w * 16 + kg * 4;
    #pragma unroll
    for (int reg = 0; reg < 4; ++reg) {
        int row = rbase + reg;
        quant_store_row(acc[0][reg], acc[1][reg], acc[2][reg], acc[3][reg],
                        row, l16, H8, scale);
    }
}

// ------------------------------------- tiered gather window (device) --------
template <int N>
__device__ __forceinline__ void gather_tier(const signed char* __restrict__ colp,
                                            int myIdx, float myS, float& acc) {
    signed char v[N];
    #pragma unroll
    for (int i = 0; i < N; ++i) {
        int r = __builtin_amdgcn_readlane(myIdx, i);             // SGPR
        v[i] = colp[(size_t)(unsigned)r << 6];                   // saddr byte load
    }
    #pragma unroll
    for (int i = 0; i < N; ++i) {
        float s = __uint_as_float(__builtin_amdgcn_readlane(__float_as_uint(myS), i));
        acc += (float)v[i] * s;
    }
}

// ---------------------------------------------------------------- aggregate -
// One wave per node, int8 table, degree-tiered window (16/24/32).
template <bool GELU>
__global__ __launch_bounds__(256) void k_aggregate(const signed char* __restrict__ hs8,
                                                   const float* __restrict__ scale,
                                                   const float* __restrict__ dinv,
                                                   const int* __restrict__ csr_src,
                                                   const unsigned int* __restrict__ rowPack,
                                                   const float* __restrict__ b,
                                                   void* __restrict__ outraw) {
    const int t = threadIdx.x;
    const int lane = t & 63;
    const int node = __builtin_amdgcn_readfirstlane(blockIdx.x * 4 + (t >> 6));
    const unsigned u = __builtin_amdgcn_readfirstlane(rowPack[node]);
    const int jS  = (int)(u >> 8);
    const int deg = (int)(u & 255u);
    const signed char* __restrict__ colp = hs8 + lane;

    const int l32 = lane & 31;
    int rr = csr_src[jS + l32];                      // coalesced vector load
    int myIdx = (l32 < deg) ? rr : N_NODES;          // zero row (scale 0)
    float myS = scale[myIdx] * dinv[myIdx];          // 4B gathers, L2-resident

    const float dn = dinv[node];
    float acc = (float)colp[(size_t)node << 6] * (scale[node] * dn);  // self

    if (deg <= 16) {
        gather_tier<16>(colp, myIdx, myS, acc);
    } else if (deg <= 24) {
        gather_tier<24>(colp, myIdx, myS, acc);
    } else {
        gather_tier<32>(colp, myIdx, myS, acc);
        if (deg > 32) {   // rare tail
            for (int j = jS + 32; j < jS + deg; ++j) {
                int r = __builtin_amdgcn_readfirstlane(csr_src[j]);
                float s = __uint_as_float(__builtin_amdgcn_readfirstlane(
                              __float_as_uint(scale[r] * dinv[r])));
                acc += (float)colp[(size_t)(unsigned)r << 6] * s;
            }
        }
    }

    float r = dn * acc + b[lane];
    if (GELU) {
        r = 0.5f * r * (1.0f + erff(r * 0.70710678118654752f));
        ((u16*)outraw)[((size_t)node << 6) + lane] = f2bf(r);
    } else {
        ((float*)outraw)[((size_t)node << 6) + lane] = r;
    }
}

// ---------------------------------------------------------------- launch ----
extern "C" void kernel_launch(void* const* d_in, const int* in_sizes, int n_in,
                              void* d_out, int out_size, void* d_ws, size_t ws_size,
                              hipStream_t stream) {
    const float* x  = (const float*)d_in[0];
    const int* edge = (const int*)d_in[1];           // [2, N_EDGES] int32
    const float* W1 = (const float*)d_in[2];
    const float* b1 = (const float*)d_in[3];
    const float* W2 = (const float*)d_in[4];
    const float* b2 = (const float*)d_in[5];
    float* out = (float*)d_out;                      // [N_NODES, 64] fp32

    const int* src = edge;
    const int* dst = edge + N_EDGES;

    char* ws = (char*)d_ws;
    int*      bucketCursor = (int*)(ws);                  // 782 ints
    int*      totalCursor  = (int*)(ws + 4096);           // 1 int (pad 8192)
    unsigned* rowPack      = (unsigned*)(ws + 8192);      // N (pad 408576)
    float*    dinv         = (float*)(ws + 408576);       // NROWS (pad 808960)
    int*      csr_src      = (int*)(ws + 808960);         // E + 64 slack (ends 7209216)
    float*    scale1       = (float*)(ws + 7209216);      // NROWS (ends 7609344)
    float*    scale2       = (float*)(ws + 7609344);      // NROWS (ends 8009472)
    signed char* hs8a      = (signed char*)(ws + 8009472);   // NROWS*64 (ends 14411520)
    signed char* hs8b      = (signed char*)(ws + 14411520);  // NROWS*64 (ends 20813568)
    u16*      out1b        = (u16*)(ws + 20813568);       // NROWS*64 bf16 (ends 33617664)
    unsigned* bins         = (unsigned*)out1b;            // 8.13MB alias, dead before agg1
    u16*      w1pre        = (u16*)(ws + 33617664);       // 32 KB
    u16*      w2pre        = (u16*)(ws + 33650432);       // 16 KB

    const int nBlkAgg = N_NODES / 4;                      // 25000

    // 1. weight pre-split + cursor zeroing
    k_pre<<<32, 256, 0, stream>>>(W1, W2, w1pre, w2pre, bucketCursor, totalCursor, dinv);
    // 2. fused edge binning + GEMM1 (48KB LDS -> 3 blocks/CU)
    k_bin_gemm1<<<NBINBLK + NGEMMBLK, 256, 0, stream>>>(src, dst, bucketCursor, bins,
                                                        x, w1pre, hs8a, scale1);
    // 3. CSR build (ticket-based, packed row_start|deg)
    k_build<<<NBUK, 256, 0, stream>>>(bins, bucketCursor, totalCursor, rowPack, dinv, csr_src);
    // 4. aggregate layer 1 (+bias+GELU) -> bf16
    k_aggregate<true><<<nBlkAgg, 256, 0, stream>>>(hs8a, scale1, dinv, csr_src, rowPack, b1, out1b);
    // 5. GEMM2 -> int8+scale
    k_gemm2<<<NGEMMBLK, 256, 0, stream>>>(out1b, w2pre, hs8b, scale2);
    // 6. aggregate layer 2 (+bias) -> fp32 out
    k_aggregate<false><<<nBlkAgg, 256, 0, stream>>>(hs8b, scale2, dinv, csr_src, rowPack, b2, out);
}

// Round 23
// 146.501 us; speedup vs baseline: 1.1170x; 1.0091x over previous
//
#include <hip/hip_runtime.h>
#include <math.h>

#define N_NODES 100000
#define N_EDGES 1600000
#define NROWS 100032
#define NBUK 782          // dst>>7 -> 0..781 (128 nodes per bucket)
#define BCAP 2600         // entries per bucket region (mean 2046)
#define BINCHUNK 4096     // edges per bin block (256 thr x 16)
#define NBINBLK 391
#define NGEMMBLK 1563     // NROWS/64

typedef unsigned short u16;
typedef u16 u16x4 __attribute__((ext_vector_type(4)));
typedef u16 u16x8 __attribute__((ext_vector_type(8)));
typedef short s16x8 __attribute__((ext_vector_type(8)));
typedef float f32x4 __attribute__((ext_vector_type(4)));

__device__ __forceinline__ float bf2f(u16 u) {
    union { unsigned i; float f; } v; v.i = ((unsigned)u) << 16; return v.f;
}
__device__ __forceinline__ u16 f2bf(float f) {
    union { float f; unsigned i; } v; v.f = f;
    return (u16)((v.i + 0x7FFFu + ((v.i >> 16) & 1u)) >> 16);  // RNE
}

// ------------------------- pre: W split + cursor zeroing (one dispatch) -----
__global__ __launch_bounds__(256) void k_pre(const float* __restrict__ W1,
                                             const float* __restrict__ W2,
                                             u16* __restrict__ w1pre,
                                             u16* __restrict__ w2pre,
                                             int* __restrict__ bucketCursor,
                                             int* __restrict__ totalCursor,
                                             float* __restrict__ dinv) {
    const int t = threadIdx.x;
    const int b = blockIdx.x;
    if (b < 16) {
        #pragma unroll
        for (int half = 0; half < 2; ++half) {
            int e = b * 512 + half * 256 + t;   // e = k*64 + c
            int k = e >> 6, c = e & 63;
            float f = W1[e];
            u16 h = f2bf(f);
            u16 l = f2bf(f - bf2f(h));
            int byte = (c * 256 + k * 2) ^ ((c & 7) << 4);
            *(u16*)((char*)w1pre + byte) = h;
            *(u16*)((char*)w1pre + 16384 + byte) = l;
        }
    } else {
        int e = (b - 16) * 256 + t;
        int k = e >> 6, c = e & 63;
        float f = W2[e];
        u16 h = f2bf(f);
        u16 l = f2bf(f - bf2f(h));
        int byte = (c * 128 + k * 2) ^ ((c & 7) << 4);
        *(u16*)((char*)w2pre + byte) = h;
        *(u16*)((char*)w2pre + 8192 + byte) = l;
    }
    if (b == 0) {
        for (int i = t; i < NBUK; i += 256) bucketCursor[i] = 0;
        if (t == 0) { totalCursor[0] = 0; dinv[N_NODES] = 0.f; }
    }
}

// -------------------------------- quantized-row epilogue helper (device) ----
__device__ __forceinline__ void quant_store_row(float v0, float v1, float v2, float v3,
                                                int row, int l16,
                                                signed char* __restrict__ H8,
                                                float* __restrict__ scale) {
    float m = fmaxf(fmaxf(fabsf(v0), fabsf(v1)), fmaxf(fabsf(v2), fabsf(v3)));
    m = fmaxf(m, __shfl_xor(m, 1));
    m = fmaxf(m, __shfl_xor(m, 2));
    m = fmaxf(m, __shfl_xor(m, 4));
    m = fmaxf(m, __shfl_xor(m, 8));
    float inv = (m > 0.f) ? 127.f / m : 0.f;
    if (l16 == 0) scale[row] = m * (1.f / 127.f);
    size_t base = (size_t)row * 64 + l16;
    H8[base +  0] = (signed char)__float2int_rn(v0 * inv);
    H8[base + 16] = (signed char)__float2int_rn(v1 * inv);
    H8[base + 32] = (signed char)__float2int_rn(v2 * inv);
    H8[base + 48] = (signed char)__float2int_rn(v3 * inv);
}

// ------------------- fused: edge binning (blocks<391) + GEMM1 (rest) --------
// 32KB LDS: BOTH x and W staged in K=64 halves (8+8 KB each)
// -> 5 blocks/CU (was 3 at 48KB).
__global__ __launch_bounds__(256) void k_bin_gemm1(const int* __restrict__ src,
                                                   const int* __restrict__ dst,
                                                   int* bucketCursor,
                                                   unsigned int* __restrict__ bins,
                                                   const float* __restrict__ X,
                                                   const u16* __restrict__ w1pre,
                                                   signed char* __restrict__ H8,
                                                   float* __restrict__ scale) {
    __shared__ __align__(16) char smem[32768];
    const int t = threadIdx.x;

    if (blockIdx.x < NBINBLK) {
        // ---------------- bin part (8KB of smem) ----------------
        int* lcnt  = (int*)smem;
        int* lbase = (int*)(smem + 4096);
        for (int i = t; i < NBUK; i += 256) lcnt[i] = 0;
        __syncthreads();

        const int e0 = blockIdx.x * BINCHUNK + t * 16;
        int4 s4[4], d4[4];
        int bkt[16], rnk[16];
        const bool valid = e0 < N_EDGES;
        if (valid) {
            #pragma unroll
            for (int k = 0; k < 4; ++k) {
                s4[k] = *(const int4*)(src + e0 + 4 * k);
                d4[k] = *(const int4*)(dst + e0 + 4 * k);
            }
            #pragma unroll
            for (int k = 0; k < 4; ++k) {
                int dd[4] = { d4[k].x, d4[k].y, d4[k].z, d4[k].w };
                #pragma unroll
                for (int j = 0; j < 4; ++j) {
                    int b = dd[j] >> 7;
                    bkt[4 * k + j] = b;
                    rnk[4 * k + j] = atomicAdd(&lcnt[b], 1);
                }
            }
        }
        __syncthreads();
        for (int i = t; i < NBUK; i += 256)
            if (lcnt[i] > 0) lbase[i] = atomicAdd(&bucketCursor[i], lcnt[i]);
        __syncthreads();
        if (valid) {
            #pragma unroll
            for (int k = 0; k < 4; ++k) {
                int ss[4] = { s4[k].x, s4[k].y, s4[k].z, s4[k].w };
                int dd[4] = { d4[k].x, d4[k].y, d4[k].z, d4[k].w };
                #pragma unroll
                for (int j = 0; j < 4; ++j) {
                    int i = 4 * k + j;
                    unsigned w = ((unsigned)(dd[j] & 127) << 17) | (unsigned)ss[j];
                    bins[(size_t)bkt[i] * BCAP + lbase[bkt[i]] + rnk[i]] = w;
                }
            }
        }
        return;
    }

    // ---------------- gemm1 part ----------------
    u16* sxh = (u16*)smem;              //  8KB: x hi half (64 rows x 64 k)
    u16* sxl = (u16*)(smem +  8192);    //  8KB: x lo half
    u16* wth = (u16*)(smem + 16384);    //  8KB: W hi half (64 c x 64 k)
    u16* wtl = (u16*)(smem + 24576);    //  8KB: W lo half
    const int blk = blockIdx.x - NBINBLK;

    const int lane = t & 63;
    const int w    = t >> 6;
    const int l16  = lane & 15;
    const int kg   = lane >> 4;
    f32x4 acc[4];
    #pragma unroll
    for (int nt = 0; nt < 4; ++nt)
        #pragma unroll
        for (int j = 0; j < 4; ++j) acc[nt][j] = 0.f;

    const int arow = w * 16 + l16;
    const int aswz = (arow & 7) << 4;
    const float4* Xv = (const float4*)X;
    const u16x8* G = (const u16x8*)w1pre;   // hi at vec[0..1024), lo at +1024

    #pragma unroll
    for (int kh = 0; kh < 2; ++kh) {
        if (kh) __syncthreads();   // protect previous half's reads
        // stage x half: 64 rows x 64 cols fp32 -> hi/lo bf16 (1024 float4)
        #pragma unroll
        for (int i = 0; i < 4; ++i) {
            int idx = i * 256 + t;
            int row = idx >> 4;              // 16 float4 per row
            int c4  = idx & 15;
            int grow = blk * 64 + row;
            float4 v = make_float4(0.f, 0.f, 0.f, 0.f);
            if (grow < N_NODES) v = Xv[(size_t)grow * 32 + kh * 16 + c4];
            float f[4] = { v.x, v.y, v.z, v.w };
            u16x4 hv, lv;
            #pragma unroll
            for (int j = 0; j < 4; ++j) {
                u16 h = f2bf(f[j]);
                hv[j] = h;
                lv[j] = f2bf(f[j] - bf2f(h));
            }
            int byte = (row * 128 + c4 * 8) ^ ((row & 7) << 4);
            *(u16x4*)((char*)sxh + byte) = hv;
            *(u16x4*)((char*)sxl + byte) = lv;
        }
        // stage W half: direct 16B copy; per-column 128B sub-block of w1pre
        // (swizzle is internal to the sub-block, so layout carries over)
        {
            u16x8* Lh = (u16x8*)wth;
            u16x8* Ll = (u16x8*)wtl;
            #pragma unroll
            for (int i = 0; i < 2; ++i) {
                int idx = i * 256 + t;       // < 512
                int c = idx >> 3, j = idx & 7;
                Lh[idx] = G[c * 16 + kh * 8 + j];
                Ll[idx] = G[1024 + c * 16 + kh * 8 + j];
            }
        }
        __syncthreads();

        #pragma unroll
        for (int kt = 0; kt < 2; ++kt) {
            const int koffA = kt * 64 + kg * 16;            // local bytes (0..127)
            s16x8 ah = *(const s16x8*)((const char*)sxh + ((arow * 128 + koffA) ^ aswz));
            s16x8 al = *(const s16x8*)((const char*)sxl + ((arow * 128 + koffA) ^ aswz));
            #pragma unroll
            for (int nt = 0; nt < 4; ++nt) {
                const int c = nt * 16 + l16;
                const int wb = (c * 128 + koffA) ^ ((c & 7) << 4);
                s16x8 bh = *(const s16x8*)((const char*)wth + wb);
                s16x8 bl = *(const s16x8*)((const char*)wtl + wb);
                acc[nt] = __builtin_amdgcn_mfma_f32_16x16x32_bf16(ah, bh, acc[nt], 0, 0, 0);
                acc[nt] = __builtin_amdgcn_mfma_f32_16x16x32_bf16(ah, bl, acc[nt], 0, 0, 0);
                acc[nt] = __builtin_amdgcn_mfma_f32_16x16x32_bf16(al, bh, acc[nt], 0, 0, 0);
            }
        }
    }

    const int rbase = blk * 64 + w * 16 + kg * 4;
    #pragma unroll
    for (int reg = 0; reg < 4; ++reg) {
        int row = rbase + reg;
        quant_store_row(acc[0][reg], acc[1][reg], acc[2][reg], acc[3][reg],
                        row, l16, H8, scale);
    }
}

// ------------- per-bucket CSR build: atomic-ticket base, packed row ---------
__global__ __launch_bounds__(256) void k_build(const unsigned int* __restrict__ bins,
                                               const int* __restrict__ bucketCursor,
                                               int* totalCursor,
                                               unsigned int* __restrict__ rowPack,
                                               float* __restrict__ dinv,
                                               int* __restrict__ csr_src) {
    __shared__ int cnt[128];
    __shared__ int ps[128];
    __shared__ int cur[128];
    __shared__ int gbS;
    const int b = blockIdx.x;
    const int t = threadIdx.x;
    const int bcnt = bucketCursor[b];
    const unsigned int* mybins = bins + (size_t)b * BCAP;

    if (t == 0) gbS = atomicAdd(totalCursor, bcnt);
    if (t < 128) cnt[t] = 0;
    __syncthreads();
    for (int i = t; i < bcnt; i += 256)
        atomicAdd(&cnt[mybins[i] >> 17], 1);
    __syncthreads();
    if (t < 128) ps[t] = cnt[t];
    __syncthreads();
    #pragma unroll
    for (int off = 1; off < 128; off <<= 1) {
        int x = (t >= off && t < 128) ? ps[t - off] : 0;
        __syncthreads();
        if (t < 128) ps[t] += x;
        __syncthreads();
    }
    const int gb = gbS;
    if (t < 128) {
        int excl = (t > 0) ? ps[t - 1] : 0;
        cur[t] = excl;
        int node = (b << 7) + t;
        if (node < N_NODES) {
            rowPack[node] = ((unsigned)(gb + excl) << 8) | (unsigned)cnt[t];
            dinv[node] = rsqrtf((float)(cnt[t] + 1));
        }
    }
    __syncthreads();
    for (int i = t; i < bcnt; i += 256) {
        unsigned w = mybins[i];
        int dl = w >> 17;
        int s = (int)(w & 0x1FFFFu);
        int p = atomicAdd(&cur[dl], 1);
        csr_src[gb + p] = s;
    }
}

// ------------------------------------------------------- GEMM2 (MFMA) -------
__global__ __launch_bounds__(256) void k_gemm2(const u16* __restrict__ Xb,
                                               const u16* __restrict__ w2pre,
                                               signed char* __restrict__ H8,
                                               float* __restrict__ scale) {
    __shared__ u16 sxb[64 * 64];
    __shared__ u16 wth[64 * 64];
    __shared__ u16 wtl[64 * 64];
    const int t = threadIdx.x;
    const int blk = blockIdx.x;

    {
        const u16x8* Xv = (const u16x8*)Xb;
        #pragma unroll
        for (int i = 0; i < 2; ++i) {
            int idx = i * 256 + t;
            int row = idx >> 3;
            int k0  = (idx & 7) << 3;
            int grow = blk * 64 + row;
            u16x8 v;
            #pragma unroll
            for (int j = 0; j < 8; ++j) v[j] = 0;
            if (grow < N_NODES) v = Xv[(size_t)grow * 8 + (idx & 7)];
            int byte = (row * 128 + k0 * 2) ^ ((row & 7) << 4);
            *(u16x8*)((char*)sxb + byte) = v;
        }
    }
    {
        const u16x8* G = (const u16x8*)w2pre;
        u16x8* Lh = (u16x8*)wth;
        u16x8* Ll = (u16x8*)wtl;
        #pragma unroll
        for (int i = 0; i < 2; ++i) Lh[i * 256 + t] = G[i * 256 + t];
        #pragma unroll
        for (int i = 0; i < 2; ++i) Ll[i * 256 + t] = G[512 + i * 256 + t];
    }
    __syncthreads();

    const int lane = t & 63;
    const int w    = t >> 6;
    const int l16  = lane & 15;
    const int kg   = lane >> 4;
    f32x4 acc[4];
    #pragma unroll
    for (int nt = 0; nt < 4; ++nt)
        #pragma unroll
        for (int j = 0; j < 4; ++j) acc[nt][j] = 0.f;

    const int arow = w * 16 + l16;
    const int aswz = (arow & 7) << 4;
    #pragma unroll
    for (int kt = 0; kt < 2; ++kt) {
        const int koff = kt * 64 + kg * 16;
        s16x8 a = *(const s16x8*)((const char*)sxb + ((arow * 128 + koff) ^ aswz));
        #pragma unroll
        for (int nt = 0; nt < 4; ++nt) {
            const int c = nt * 16 + l16;
            const int wb = (c * 128 + koff) ^ ((c & 7) << 4);
            s16x8 bh = *(const s16x8*)((const char*)wth + wb);
            s16x8 bl = *(const s16x8*)((const char*)wtl + wb);
            acc[nt] = __builtin_amdgcn_mfma_f32_16x16x32_bf16(a, bh, acc[nt], 0, 0, 0);
            acc[nt] = __builtin_amdgcn_mfma_f32_16x16x32_bf16(a, bl, acc[nt], 0, 0, 0);
        }
    }
    const int rbase = blk * 64 + w * 16 + kg * 4;
    #pragma unroll
    for (int reg = 0; reg < 4; ++reg) {
        int row = rbase + reg;
        quant_store_row(acc[0][reg], acc[1][reg], acc[2][reg], acc[3][reg],
                        row, l16, H8, scale);
    }
}

// ------------------------------------- tiered gather window (device) --------
template <int N>
__device__ __forceinline__ void gather_tier(const signed char* __restrict__ colp,
                                            int myIdx, float myS, float& acc) {
    signed char v[N];
    #pragma unroll
    for (int i = 0; i < N; ++i) {
        int r = __builtin_amdgcn_readlane(myIdx, i);             // SGPR
        v[i] = colp[(size_t)(unsigned)r << 6];                   // saddr byte load
    }
    #pragma unroll
    for (int i = 0; i < N; ++i) {
        float s = __uint_as_float(__builtin_amdgcn_readlane(__float_as_uint(myS), i));
        acc += (float)v[i] * s;
    }
}

// ---------------------------------------------------------------- aggregate -
// One wave per node, int8 table, degree-tiered window (16/24/32).
template <bool GELU>
__global__ __launch_bounds__(256) void k_aggregate(const signed char* __restrict__ hs8,
                                                   const float* __restrict__ scale,
                                                   const float* __restrict__ dinv,
                                                   const int* __restrict__ csr_src,
                                                   const unsigned int* __restrict__ rowPack,
                                                   const float* __restrict__ b,
                                                   void* __restrict__ outraw) {
    const int t = threadIdx.x;
    const int lane = t & 63;
    const int node = __builtin_amdgcn_readfirstlane(blockIdx.x * 4 + (t >> 6));
    const unsigned u = __builtin_amdgcn_readfirstlane(rowPack[node]);
    const int jS  = (int)(u >> 8);
    const int deg = (int)(u & 255u);
    const signed char* __restrict__ colp = hs8 + lane;

    const int l32 = lane & 31;
    int rr = csr_src[jS + l32];                      // coalesced vector load
    int myIdx = (l32 < deg) ? rr : N_NODES;          // zero row (scale 0)
    float myS = scale[myIdx] * dinv[myIdx];          // 4B gathers, L2-resident

    const float dn = dinv[node];
    float acc = (float)colp[(size_t)node << 6] * (scale[node] * dn);  // self

    if (deg <= 16) {
        gather_tier<16>(colp, myIdx, myS, acc);
    } else if (deg <= 24) {
        gather_tier<24>(colp, myIdx, myS, acc);
    } else {
        gather_tier<32>(colp, myIdx, myS, acc);
        if (deg > 32) {   // rare tail
            for (int j = jS + 32; j < jS + deg; ++j) {
                int r = __builtin_amdgcn_readfirstlane(csr_src[j]);
                float s = __uint_as_float(__builtin_amdgcn_readfirstlane(
                              __float_as_uint(scale[r] * dinv[r])));
                acc += (float)colp[(size_t)(unsigned)r << 6] * s;
            }
        }
    }

    float r = dn * acc + b[lane];
    if (GELU) {
        r = 0.5f * r * (1.0f + erff(r * 0.70710678118654752f));
        ((u16*)outraw)[((size_t)node << 6) + lane] = f2bf(r);
    } else {
        ((float*)outraw)[((size_t)node << 6) + lane] = r;
    }
}

// ---------------------------------------------------------------- launch ----
extern "C" void kernel_launch(void* const* d_in, const int* in_sizes, int n_in,
                              void* d_out, int out_size, void* d_ws, size_t ws_size,
                              hipStream_t stream) {
    const float* x  = (const float*)d_in[0];
    const int* edge = (const int*)d_in[1];           // [2, N_EDGES] int32
    const float* W1 = (const float*)d_in[2];
    const float* b1 = (const float*)d_in[3];
    const float* W2 = (const float*)d_in[4];
    const float* b2 = (const float*)d_in[5];
    float* out = (float*)d_out;                      // [N_NODES, 64] fp32

    const int* src = edge;
    const int* dst = edge + N_EDGES;

    char* ws = (char*)d_ws;
    int*      bucketCursor = (int*)(ws);                  // 782 ints
    int*      totalCursor  = (int*)(ws + 4096);           // 1 int (pad 8192)
    unsigned* rowPack      = (unsigned*)(ws + 8192);      // N (pad 408576)
    float*    dinv         = (float*)(ws + 408576);       // NROWS (pad 808960)
    int*      csr_src      = (int*)(ws + 808960);         // E + 64 slack (ends 7209216)
    float*    scale1       = (float*)(ws + 7209216);      // NROWS (ends 7609344)
    float*    scale2       = (float*)(ws + 7609344);      // NROWS (ends 8009472)
    signed char* hs8a      = (signed char*)(ws + 8009472);   // NROWS*64 (ends 14411520)
    signed char* hs8b      = (signed char*)(ws + 14411520);  // NROWS*64 (ends 20813568)
    u16*      out1b        = (u16*)(ws + 20813568);       // NROWS*64 bf16 (ends 33617664)
    unsigned* bins         = (unsigned*)out1b;            // 8.13MB alias, dead before agg1
    u16*      w1pre        = (u16*)(ws + 33617664);       // 32 KB
    u16*      w2pre        = (u16*)(ws + 33650432);       // 16 KB

    const int nBlkAgg = N_NODES / 4;                      // 25000

    // 1. weight pre-split + cursor zeroing
    k_pre<<<32, 256, 0, stream>>>(W1, W2, w1pre, w2pre, bucketCursor, totalCursor, dinv);
    // 2. fused edge binning + GEMM1 (32KB LDS -> 5 blocks/CU)
    k_bin_gemm1<<<NBINBLK + NGEMMBLK, 256, 0, stream>>>(src, dst, bucketCursor, bins,
                                                        x, w1pre, hs8a, scale1);
    // 3. CSR build (ticket-based, packed row_start|deg)
    k_build<<<NBUK, 256, 0, stream>>>(bins, bucketCursor, totalCursor, rowPack, dinv, csr_src);
    // 4. aggregate layer 1 (+bias+GELU) -> bf16
    k_aggregate<true><<<nBlkAgg, 256, 0, stream>>>(hs8a, scale1, dinv, csr_src, rowPack, b1, out1b);
    // 5. GEMM2 -> int8+scale
    k_gemm2<<<NGEMMBLK, 256, 0, stream>>>(out1b, w2pre, hs8b, scale2);
    // 6. aggregate layer 2 (+bias) -> fp32 out
    k_aggregate<false><<<nBlkAgg, 256, 0, stream>>>(hs8b, scale2, dinv, csr_src, rowPack, b2, out);
}